// Round 18
// baseline (863.172 us; speedup 1.0000x reference)
//
#include <hip/hip_runtime.h>
#include <hip/hip_bf16.h>
#include <math.h>

// LinearAttentionLayerOptimized: B=4, T=2048, C=1024, H=16, N=64, L=128, E=1228
// Round 17: round-16 base (best, 862.0us) + triangular-tile skipping in the
// recurrence: 6/16 tiles of AT/BM/P2t/GRt are entirely zero (s-block>t-block,
// wave-uniform skip, zeros still written), and phase6a's a2/a3 s4-loop
// truncates to 2*(wid&3)+2 (drops exact-zero products; bit-identical fp32).
// ~19% of the recurrence's LDS issue (its measured bottleneck) removed.
// Everything else byte-identical to round 16.

#define BB 4
#define TT 2048
#define CC 1024
#define HH 16
#define NN 64
#define LL 128
#define EE 1228
#define EPAD 1280
#define MM (BB*TT)          // 8192 rows
#define TCH 32
#define NSEG 4
#define WARMCH 2            // 64 warm-up steps; decay<=0.82 -> ~3e-6
#define DECAY_C_F 0.7408182206817179f

typedef __attribute__((ext_vector_type(8))) short s16x8;
typedef __attribute__((ext_vector_type(4))) float f32x4;

#define GLOAD_LDS16(gp, lp) \
    __builtin_amdgcn_global_load_lds((const __attribute__((address_space(1))) void*)(gp), \
                                     (__attribute__((address_space(3))) void*)(lp), 16, 0, 0)

__device__ __forceinline__ float fast_sigmoid(float w) {
    return __fdividef(1.0f, 1.0f + __expf(-w));
}
// tanh-form gelu: x*sigma(1.59576912*x*(1+0.044715x^2))
__device__ __forceinline__ float fast_gelu(float x) {
    float x2 = x * x;
    float w = 1.59576912f * x * fmaf(0.044715f, x2, 1.0f);
    return x * fast_sigmoid(w);
}
__device__ __forceinline__ float fast_decay(float x) {
    float t = fmaf(2.0f, fast_sigmoid(2.0f * x), -1.0f);   // tanh(x)
    float sg = fast_sigmoid(t);
    return __expf(-DECAY_C_F * sg);
}

// ---------------- z-batched two-pass bias folds ----------------
__global__ __launch_bounds__(256) void fold_pass1_z(
    const float* __restrict__ mu0, const float* __restrict__ mu1, const float* __restrict__ mu2,
    const float* __restrict__ W0,  const float* __restrict__ W1_, const float* __restrict__ W2_,
    float* __restrict__ partial, int ldW, int E, int ldP, int pslice) {
    const float* mu = blockIdx.z == 0 ? mu0 : (blockIdx.z == 1 ? mu1 : mu2);
    const float* W  = blockIdx.z == 0 ? W0  : (blockIdx.z == 1 ? W1_ : W2_);
    partial += (size_t)blockIdx.z * pslice;
    const int l = threadIdx.x & 63;
    const int e = blockIdx.x * 64 + l;
    const int pg = threadIdx.x >> 6;
    const int c0 = blockIdx.y * 64;
    float s = 0.f;
    if (e < E)
        for (int c = c0 + pg; c < c0 + 64; c += 4) s += mu[c] * W[(size_t)c * ldW + e];
    __shared__ float red[4][64];
    red[pg][l] = s;
    __syncthreads();
    if (pg == 0 && e < E)
        partial[(size_t)blockIdx.y * ldP + e] = red[0][l] + red[1][l] + red[2][l] + red[3][l];
}

__global__ void fold_pass2_z(const float* __restrict__ partial,
                             const float* b0, const float* b1, const float* b2,
                             float* __restrict__ outv,
                             int P, int ldP, int pslice, int E, int Epad, int oslice) {
    const float* bias = blockIdx.z == 0 ? b0 : (blockIdx.z == 1 ? b1 : b2);
    partial += (size_t)blockIdx.z * pslice;
    outv    += (size_t)blockIdx.z * oslice;
    int e = blockIdx.x * blockDim.x + threadIdx.x;
    if (e >= Epad) return;
    float s = 0.f;
    if (e < E) {
        s = bias ? bias[e] : 0.f;
        for (int p = 0; p < P; ++p) s += partial[(size_t)p * ldP + e];
    }
    outv[e] = s;
}

// gather 3 bias vectors into one contiguous [3][CC] buffer
__global__ void gather3(const float* __restrict__ a, const float* __restrict__ b,
                        const float* __restrict__ c, float* __restrict__ o) {
    int i = blockIdx.x * blockDim.x + threadIdx.x;
    if (i < CC) { o[i] = a[i]; o[CC + i] = b[i]; o[2 * CC + i] = c[i]; }
}

// ---------------- cast / z-batched transpose-cast ----------------
__global__ void cast_f32_bf16(const float* __restrict__ in, __hip_bfloat16* __restrict__ out, int n4) {
    int i = blockIdx.x * blockDim.x + threadIdx.x;
    if (i >= n4) return;
    float4 v = ((const float4*)in)[i];
    __hip_bfloat16 o[4] = {__float2bfloat16(v.x), __float2bfloat16(v.y),
                           __float2bfloat16(v.z), __float2bfloat16(v.w)};
    *(ulong1*)&out[i * 4] = *(ulong1*)o;
}

__global__ void transpose_cast_z(const float* s0, const float* s1, const float* s2,
                                 __hip_bfloat16* __restrict__ outT, size_t dslice,
                                 int Rin, int Cin, int Rpad, int Cpad) {
    const float* in = blockIdx.z == 0 ? s0 : (blockIdx.z == 1 ? s1 : s2);
    outT += (size_t)blockIdx.z * dslice;
    __shared__ float t[32][33];
    const int r0 = blockIdx.x * 32, c0 = blockIdx.y * 32;
    const int tx = threadIdx.x, ty = threadIdx.y;   // 32 x 8
    #pragma unroll
    for (int j = 0; j < 4; ++j) {
        int r = r0 + ty + j * 8, c = c0 + tx;
        t[ty + j * 8][tx] = (r < Rin && c < Cin) ? in[(size_t)r * Cin + c] : 0.f;
    }
    __syncthreads();
    #pragma unroll
    for (int j = 0; j < 4; ++j) {
        int c = c0 + ty + j * 8, r = r0 + tx;
        if (c < Cpad && r < Rpad) outT[(size_t)c * Rpad + r] = __float2bfloat16(t[tx][ty + j * 8]);
    }
}

// ---------------- bf16 MFMA GEMM, BK=64 (z-batched, per-z activation) ----------------
template<int ACT, int ACTZ2, int OBF, int PADZ>
__global__ __launch_bounds__(256) void gemm_mfma(const __hip_bfloat16* __restrict__ A,
                                                 const __hip_bfloat16* __restrict__ Bt,
                                                 const float* __restrict__ bias,
                                                 void* __restrict__ Cptr,
                                                 int M, int N, int K,
                                                 int ldA, int ldB, int ldC,
                                                 size_t zA, size_t zB, size_t zBias, size_t zC) {
    __shared__ __hip_bfloat16 As[128 * 64];   // 16 KB
    __shared__ __hip_bfloat16 Bs[128 * 64];   // 16 KB
    const int tid = threadIdx.x;
    const int wid = tid >> 6, lane = tid & 63;
    const int wm = wid >> 1, wn = wid & 1;
    const int bm = blockIdx.y * 128, bn = blockIdx.x * 128;
    A  += (size_t)blockIdx.z * zA;
    Bt += (size_t)blockIdx.z * zB;
    if (bias) bias += (size_t)blockIdx.z * zBias;
    const size_t zc = (size_t)blockIdx.z * zC;
    const int act = (ACTZ2 >= 0 && blockIdx.z == 2) ? ACTZ2 : ACT;

    const __hip_bfloat16* srcA[4];
    const __hip_bfloat16* srcB[4];
    #pragma unroll
    for (int i = 0; i < 4; ++i) {
        int off = (wid * 4 + i) * 1024 + lane * 16;
        int r = off >> 7;            // 128 B rows
        int c = (off >> 4) & 7;      // chunk position
        int cs = c ^ (r & 7);        // source chunk
        srcA[i] = A  + (size_t)(bm + r) * ldA + cs * 8;
        srcB[i] = Bt + (size_t)(bn + r) * ldB + cs * 8;
    }

    f32x4 acc[4][4];
    #pragma unroll
    for (int i = 0; i < 4; ++i)
        #pragma unroll
        for (int j = 0; j < 4; ++j) acc[i][j] = (f32x4){0.f, 0.f, 0.f, 0.f};

    const int ra = wm * 64 + (lane & 15);
    const int rb = wn * 64 + (lane & 15);

    for (int k0 = 0; k0 < K; k0 += 64) {
        #pragma unroll
        for (int i = 0; i < 4; ++i) {
            GLOAD_LDS16(srcA[i] + k0, (char*)As + (wid * 4 + i) * 1024);
            GLOAD_LDS16(srcB[i] + k0, (char*)Bs + (wid * 4 + i) * 1024);
        }
        __syncthreads();
        #pragma unroll
        for (int h = 0; h < 2; ++h) {
            s16x8 af[4], bfr[4];
            const int kc = (lane >> 4) + h * 4;
            #pragma unroll
            for (int mi = 0; mi < 4; ++mi) {
                int r = ra + mi * 16;
                af[mi] = *(const s16x8*)((const char*)As + r * 128 + (kc ^ (r & 7)) * 16);
            }
            #pragma unroll
            for (int ni = 0; ni < 4; ++ni) {
                int r = rb + ni * 16;
                bfr[ni] = *(const s16x8*)((const char*)Bs + r * 128 + (kc ^ (r & 7)) * 16);
            }
            #pragma unroll
            for (int mi = 0; mi < 4; ++mi)
                #pragma unroll
                for (int ni = 0; ni < 4; ++ni)
                    acc[mi][ni] = __builtin_amdgcn_mfma_f32_16x16x32_bf16(af[mi], bfr[ni], acc[mi][ni], 0, 0, 0);
        }
        __syncthreads();
    }

    #pragma unroll
    for (int ni = 0; ni < 4; ++ni) {
        const int col = bn + wn * 64 + ni * 16 + (lane & 15);
        const bool valid = (col < N);
        const float bc = (valid && bias) ? bias[col] : 0.f;
        #pragma unroll
        for (int mi = 0; mi < 4; ++mi) {
            #pragma unroll
            for (int reg = 0; reg < 4; ++reg) {
                const int row = bm + wm * 64 + mi * 16 + (lane >> 4) * 4 + reg;
                float y = 0.f;
                if (valid) {
                    float x = acc[mi][ni][reg] + bc;
                    if (act == 1)      y = fast_gelu(x);
                    else if (act == 2) y = fast_sigmoid(x);
                    else if (act == 3) y = fast_decay(x);
                    else               y = x;
                }
                if (valid || PADZ) {
                    if (OBF) ((__hip_bfloat16*)Cptr)[zc + (size_t)row * ldC + col] = __float2bfloat16(y);
                    else     ((float*)Cptr)[zc + (size_t)row * ldC + col] = y;
                }
            }
        }
    }
}

// ---------------- segment-parallel chunked recurrence (512 threads, 8 waves) ----------------
#define P_T0(i,j)   pool[0     + (i)*68 + (j)]
#define P_WT(i,j)   pool[4352  + (i)*68 + (j)]
#define P_KP(i,j)   pool[6528  + (i)*68 + (j)]
#define P_P2t(i,j)  pool[6528  + (i)*36 + (j)]   // aliases KP (dead after phase2; 6b uses KPT)
#define P_NU(i,j)   pool[8704  + (i)*68 + (j)]
#define P_GRt(i,j)  pool[8704  + (i)*36 + (j)]   // aliases NU (dead after phase2; 6b uses NUT)
#define P_RKM(i,j)  pool[10880 + (i)*68 + (j)]
#define P_RRM(i,j)  pool[13056 + (i)*68 + (j)]
#define P_GM(i,j)   pool[15232 + (i)*68 + (j)]
// hole @17408 (was GMT - deleted)
#define P_KPT(i,j)  pool[19712 + (i)*36 + (j)]
#define P_NUT(i,j)  pool[22016 + (i)*36 + (j)]
// hole @24320 (was RKMT - deleted)
#define P_DCT(i,j)  pool[26624 + (i)*36 + (j)]
#define P_AT(i,j)   pool[28928 + (i)*36 + (j)]
#define P_BM(i,j)   pool[30080 + (i)*36 + (j)]
#define P_SEG(i,j)  pool[31232 + (i)*64 + (j)]
#define LD4(expr)   (*(const float4*)&(expr))
#define FMA4(acc, s, v) { (acc).x = fmaf((s), (v).x, (acc).x); (acc).y = fmaf((s), (v).y, (acc).y); \
                          (acc).z = fmaf((s), (v).z, (acc).z); (acc).w = fmaf((s), (v).w, (acc).w); }
#define DOT4(a, b) ((a).x*(b).x + (a).y*(b).y + (a).z*(b).z + (a).w*(b).w)

__global__ __launch_bounds__(512) void recurrence_chunked(
    const __hip_bfloat16* __restrict__ kbuf, const __hip_bfloat16* __restrict__ iclr,
    const __hip_bfloat16* __restrict__ dbuf, const __hip_bfloat16* __restrict__ vbuf,
    const __hip_bfloat16* __restrict__ rbuf,
    const float* __restrict__ rem_mult, const float* __restrict__ iclr_mix,
    const float* __restrict__ bonus_mult, __hip_bfloat16* __restrict__ outb) {
    __shared__ float pool[31488];   // 123 KB
    const int bh = blockIdx.x & 63, seg = blockIdx.x >> 6;
    const int b = bh >> 4, h = bh & 15;
    const int tid = threadIdx.x, lane = tid & 63, wid = tid >> 6;
    const size_t gbase = ((size_t)b * TT) * CC + (size_t)h * NN;

    for (int i = tid; i < 4352; i += 512) pool[i] = 0.f;   // T0 = 0 at segment start
    const int c0 = tid & 63;
    const float remc = rem_mult[h * NN + c0];
    const float mixc = iclr_mix[h * NN + c0];
    __syncthreads();

    // stagger: outputs {18,16,15,15}, warm-up 2 chunks for seg>0 -> max 18 chunks/block
    const int cout0 = (seg == 0) ? 0 : (seg == 1) ? 18 : (seg == 2) ? 34 : 49;
    const int lenq  = (seg == 0) ? 18 : (seg == 1) ? 16 : 15;
    const int ce    = cout0 + lenq;
    const int cb    = (seg == 0) ? 0 : cout0 - WARMCH;

    for (int chk = cb; chk < ce; ++chk) {
        const bool emit = (chk >= cout0);
        const int tg0 = chk * TCH;
        // ---- load & elementwise (bf16 inputs) ----
        #pragma unroll
        for (int i = 0; i < 4; ++i) {
            int idx = tid + 512 * i;
            int t = idx >> 6, c = idx & 63;
            size_t off = gbase + (size_t)(tg0 + t) * CC + c;
            float kx = __bfloat162float(kbuf[off]);
            float ax = __bfloat162float(iclr[off]);
            float rk = kx * (1.f + (ax - 1.f) * mixc);
            P_WT(t, c) = ax;
            P_KP(t, c) = kx * remc;
            P_RKM(t, c) = rk;
            P_NU(t, c) = __bfloat162float(vbuf[off]);
            if (emit) P_RRM(t, c) = __bfloat162float(rbuf[off]);
            P_DCT(c, t) = __bfloat162float(dbuf[off]);
        }
        __syncthreads();
        // ---- merged: row norms (all waves) + cumprod part1 (tid<256) ----
        #pragma unroll
        for (int rr = 0; rr < 4; ++rr) {
            int t = wid + rr * 8;
            float v = P_KP(t, lane);
            float ss = v * v;
            #pragma unroll
            for (int s = 32; s; s >>= 1) ss += __shfl_xor(ss, s);
            float kn = v / fmaxf(sqrtf(ss), 1e-12f);
            P_KP(t, lane) = kn;
            P_WT(t, lane) = P_WT(t, lane) * kn;
        }
        float lc[8];
        const int ccs = tid & 63, sgm = tid >> 6, t0s = (sgm & 3) * 8;
        if (tid < 256) {
            float pp_ = 1.f;
            #pragma unroll
            for (int j = 0; j < 8; ++j) { pp_ *= P_DCT(ccs, t0s + j); lc[j] = pp_; }
            P_SEG(sgm, ccs) = pp_;
        }
        __syncthreads();
        // ---- cumprod part2 + scaled quantities (256 threads) ----
        if (tid < 256) {
            float m = 1.f;
            for (int s = 0; s < sgm; ++s) m *= P_SEG(s, ccs);
            float dcprev = m;
            #pragma unroll
            for (int j = 0; j < 8; ++j) {
                int t = t0s + j;
                float dcur = m * lc[j];
                P_WT(t, ccs) *= dcprev;
                float inv = 1.f / dcur;
                float kap = P_KP(t, ccs) * inv; P_KP(t, ccs) = kap; P_KPT(ccs, t) = kap;
                float nu  = P_NU(t, ccs) * inv; P_NU(t, ccs) = nu;  P_NUT(ccs, t) = nu;
                P_DCT(ccs, t) = dcur;
                dcprev = dcur;
            }
        }
        __syncthreads();
        // ---- phase2: AT (2 tiles/wave) + BM (2 tiles/wave) + GM1 slab (1/wave) ----
        // AT[s][t] nonzero only s<t: tiles with s-block > t-block are entirely zero.
        #pragma unroll
        for (int u = 0; u < 2; ++u) {
            const int at = wid * 2 + u;   // 0..15
            const int sb = at >> 2, tb = at & 3;
            const int s = sb * 8 + (lane >> 3), t = tb * 8 + (lane & 7);
            if (sb > tb) { P_AT(s, t) = 0.f; continue; }
            float acc = 0.f;
            #pragma unroll
            for (int kc = 0; kc < 16; ++kc) {
                float4 a = LD4(P_KP(s, kc * 4));
                float4 bb = LD4(P_WT(t, kc * 4));
                acc += DOT4(a, bb);
            }
            P_AT(s, t) = (s < t) ? acc : 0.f;
        }
        #pragma unroll
        for (int u = 0; u < 2; ++u) {
            const int bt = wid * 2 + u;   // 0..15
            const int tb = bt >> 2, sb = bt & 3;
            const int t = tb * 8 + (lane >> 3), s = sb * 8 + (lane & 7);
            if (sb > tb) { P_BM(t, s) = 0.f; continue; }
            float acc = 0.f;
            #pragma unroll
            for (int kc = 0; kc < 16; ++kc) {
                float4 a = LD4(P_WT(t, kc * 4));
                float4 bb = LD4(P_NU(s, kc * 4));
                acc += DOT4(a, bb);
            }
            P_BM(t, s) = (s < t) ? acc : 0.f;
        }
        {   // GM1: wave owns GM rows [wid*4, wid*4+4) x all 64 q
            const int t = wid * 4 + (lane >> 4);
            const int q4 = (lane & 15) * 4;
            float4 acc = {0.f, 0.f, 0.f, 0.f};
            #pragma unroll
            for (int j4 = 0; j4 < 16; ++j4) {
                float4 w4 = LD4(P_WT(t, j4 * 4));
                float4 ta = LD4(P_T0(j4 * 4 + 0, q4));
                float4 tb = LD4(P_T0(j4 * 4 + 1, q4));
                float4 tc = LD4(P_T0(j4 * 4 + 2, q4));
                float4 td = LD4(P_T0(j4 * 4 + 3, q4));
                FMA4(acc, w4.x, ta); FMA4(acc, w4.y, tb);
                FMA4(acc, w4.z, tc); FMA4(acc, w4.w, td);
            }
            *(float4*)&P_GM(t, q4) = acc;
        }
        __syncthreads();
        // ---- phase3: GM += BM . RKM ----
        {
            const int t = wid * 4 + (lane >> 4);
            const int q4 = (lane & 15) * 4;
            float4 acc = {0.f, 0.f, 0.f, 0.f};
            #pragma unroll
            for (int s4 = 0; s4 < 8; ++s4) {
                float4 bm4 = LD4(P_BM(t, s4 * 4));
                float4 ra = LD4(P_RKM(s4 * 4 + 0, q4));
                float4 rb = LD4(P_RKM(s4 * 4 + 1, q4));
                float4 rc = LD4(P_RKM(s4 * 4 + 2, q4));
                float4 rd = LD4(P_RKM(s4 * 4 + 3, q4));
                FMA4(acc, bm4.x, ra); FMA4(acc, bm4.y, rb);
                FMA4(acc, bm4.z, rc); FMA4(acc, bm4.w, rd);
            }
            float4 g = LD4(P_GM(t, q4));
            g.x += acc.x; g.y += acc.y; g.z += acc.z; g.w += acc.w;
            *(float4*)&P_GM(t, q4) = g;
        }
        __syncthreads();
        // ---- phase4: wave0 forward substitution || waves1-7: P2t (emit only) ----
        if (wid == 0) {
            float g[32];
            #pragma unroll
            for (int t = 0; t < 32; ++t) g[t] = P_GM(t, lane);
            #pragma unroll
            for (int s = 0; s < 31; ++s) {
                #pragma unroll
                for (int t = s + 1; t < 32; ++t) g[t] -= P_AT(s, t) * g[s];
            }
            #pragma unroll
            for (int t = 0; t < 32; ++t) P_GM(t, lane) = g[t];
        } else if (emit) {
            for (int tile = wid - 1; tile < 16; tile += 7) {
                const int tb = tile >> 2, sb = tile & 3;
                int t = tb * 8 + (lane >> 3), s = sb * 8 + (lane & 7);
                if (sb > tb) { P_P2t(t, s) = 0.f; continue; }   // zero tile (s>t)
                float acc = 0.f;
                #pragma unroll
                for (int kc = 0; kc < 16; ++kc) {
                    float4 a = LD4(P_RRM(t, kc * 4));
                    float4 bb = LD4(P_RKM(s, kc * 4));
                    acc += DOT4(a, bb);
                }
                P_P2t(t, s) = (s <= t) ? acc : 0.f;
            }
        }
        __syncthreads();
        if (emit) {
            // ---- phase5: GRt[t][s] = g_s . r_t (16 tiles; skip zero tiles) ----
            for (int tile = wid; tile < 16; tile += 8) {
                const int tb = tile >> 2, sb = tile & 3;
                int t = tb * 8 + (lane >> 3), s = sb * 8 + (lane & 7);
                if (sb > tb) { P_GRt(t, s) = 0.f; continue; }
                float acc = 0.f;
                #pragma unroll
                for (int kc = 0; kc < 16; ++kc) {
                    float4 a = LD4(P_RRM(t, kc * 4));
                    float4 bb = LD4(P_GM(s, kc * 4));
                    acc += DOT4(a, bb);
                }
                P_GRt(t, s) = (s <= t) ? acc : 0.f;
            }
            __syncthreads();
            // ---- phase6a: outputs (32 tiles; s4 truncated to nonzero columns) ----
            // t-block = tile&3 = wid&3 for all 4 tiles -> uniform loop bound.
            const int s4max = 2 * (wid & 3) + 2;
            for (int tile = wid; tile < 32; tile += 8) {
                int i = (tile >> 2) * 8 + (lane >> 3), t = (tile & 3) * 8 + (lane & 7);
                float a1 = 0.f, a2 = 0.f, a3 = 0.f;
                #pragma unroll
                for (int j4 = 0; j4 < 16; ++j4) {
                    float4 a = LD4(P_T0(i, j4 * 4));
                    float4 bb = LD4(P_RRM(t, j4 * 4));
                    a1 += DOT4(a, bb);
                }
                for (int s4 = 0; s4 < s4max; ++s4) {
                    float4 a = LD4(P_NUT(i, s4 * 4));
                    float4 bb = LD4(P_P2t(t, s4 * 4));
                    a2 += DOT4(a, bb);
                    float4 c = LD4(P_KPT(i, s4 * 4));
                    float4 d = LD4(P_GRt(t, s4 * 4));
                    a3 += DOT4(c, d);
                }
                float diag = 0.2f * bonus_mult[h * NN + i] * P_NUT(i, t) * P_P2t(t, t);
                outb[gbase + (size_t)(tg0 + t) * CC + i] =
                    __float2bfloat16(P_DCT(i, t) * (a1 + a2 + diag - a3));
            }
            __syncthreads();
        }
        // ---- phase6b: T0 <- dc_end * (T0 - Kap^T G + Nu^T RK) (de-transposed slabs) ----
        #pragma unroll
        for (int u = 0; u < 2; ++u) {
            const int m = wid * 2 + u;                       // 0..15
            const int pr = (m & 7) * 8 + (lane >> 3);        // 0..63
            const int q4 = (m >> 3) * 32 + (lane & 7) * 4;   // 0..60
            float4 a1 = {0.f, 0.f, 0.f, 0.f}, a2 = {0.f, 0.f, 0.f, 0.f};
            #pragma unroll
            for (int s = 0; s < 32; ++s) {
                const float kp = P_KPT(pr, s);
                const float nu = P_NUT(pr, s);
                float4 g4 = LD4(P_GM(s, q4));
                float4 rk4 = LD4(P_RKM(s, q4));
                FMA4(a1, kp, g4);
                FMA4(a2, nu, rk4);
            }
            const float dc = P_DCT(pr, 31);
            float4 t0 = LD4(P_T0(pr, q4));
            t0.x = dc * (t0.x - a1.x + a2.x);
            t0.y = dc * (t0.y - a1.y + a2.y);
            t0.z = dc * (t0.z - a1.z + a2.z);
            t0.w = dc * (t0.w - a1.w + a2.w);
            *(float4*)&P_T0(pr, q4) = t0;
        }
        __syncthreads();
    }
}

// ---------------- LayerNorm * gate (bf16 in/out) ----------------
__global__ __launch_bounds__(256) void ln_gate_kernel(const __hip_bfloat16* __restrict__ x,
                                                      const __hip_bfloat16* __restrict__ gate,
                                                      const float* __restrict__ g,
                                                      const float* __restrict__ bv,
                                                      __hip_bfloat16* __restrict__ y) {
    const int row = blockIdx.x;
    const __hip_bfloat16* xr = x + (size_t)row * CC;
    float v[4];
    float s = 0.f;
    #pragma unroll
    for (int j = 0; j < 4; ++j) { v[j] = __bfloat162float(xr[threadIdx.x + 256 * j]); s += v[j]; }
    __shared__ float red[4], red2[4];
    #pragma unroll
    for (int o = 32; o; o >>= 1) s += __shfl_xor(s, o);
    if ((threadIdx.x & 63) == 0) red[threadIdx.x >> 6] = s;
    __syncthreads();
    const float mean = (red[0] + red[1] + red[2] + red[3]) * (1.f / CC);
    float vs = 0.f;
    #pragma unroll
    for (int j = 0; j < 4; ++j) { float d = v[j] - mean; vs += d * d; }
    #pragma unroll
    for (int o = 32; o; o >>= 1) vs += __shfl_xor(vs, o);
    if ((threadIdx.x & 63) == 0) red2[threadIdx.x >> 6] = vs;
    __syncthreads();
    const float var = (red2[0] + red2[1] + red2[2] + red2[3]) * (1.f / CC);
    const float rstd = rsqrtf(var + 1e-6f);
    #pragma unroll
    for (int j = 0; j < 4; ++j) {
        const int cc = threadIdx.x + 256 * j;
        float o_ = (v[j] - mean) * rstd * g[cc] + bv[cc];
        float gt = __bfloat162float(gate[(size_t)row * CC + cc]);
        y[(size_t)row * CC + cc] = __float2bfloat16(o_ * gt);
    }
}

// ---------------- launch ----------------
extern "C" void kernel_launch(void* const* d_in, const int* in_sizes, int n_in,
                              void* d_out, int out_size, void* d_ws, size_t ws_size,
                              hipStream_t stream) {
    const float* q        = (const float*)d_in[0];
    const float* mu_r     = (const float*)d_in[4];
    const float* mu_k     = (const float*)d_in[5];
    const float* mu_v     = (const float*)d_in[6];
    const float* mu_g     = (const float*)d_in[7];
    const float* mu_a     = (const float*)d_in[8];
    const float* mu_d     = (const float*)d_in[9];
    const float* dA       = (const float*)d_in[10];
    const float* dB       = (const float*)d_in[11];
    const float* db       = (const float*)d_in[12];
    const float* aA       = (const float*)d_in[13];
    const float* aB       = (const float*)d_in[14];
    const float* ab       = (const float*)d_in[15];
    const float* gA       = (const float*)d_in[16];
    const float* gB       = (const float*)d_in[17];
    const float* rW1      = (const float*)d_in[18];
    const float* rb1      = (const float*)d_in[19];
    const float* rW2      = (const float*)d_in[20];
    const float* rb2      = (const float*)d_in[21];
    const float* kW1      = (const float*)d_in[22];
    const float* kb1      = (const float*)d_in[23];
    const float* kW2      = (const float*)d_in[24];
    const float* kb2      = (const float*)d_in[25];
    const float* vW1      = (const float*)d_in[26];
    const float* vb1      = (const float*)d_in[27];
    const float* vW2      = (const float*)d_in[28];
    const float* vb2      = (const float*)d_in[29];
    const float* oW1      = (const float*)d_in[30];
    const float* ob1      = (const float*)d_in[31];
    const float* oW2      = (const float*)d_in[32];
    const float* ob2      = (const float*)d_in[33];
    const float* rem_mult = (const float*)d_in[34];
    const float* iclr_mix = (const float*)d_in[35];
    const float* bonus_mult = (const float*)d_in[36];
    const float* ln_g     = (const float*)d_in[37];
    const float* ln_b     = (const float*)d_in[38];
    float* out = (float*)d_out;

    // ---- workspace arena (~220 MB) ----
    char* p = (char*)d_ws;
    auto alloc = [&](size_t bytes) { char* r = p; p += (bytes + 255) & ~(size_t)255; return r; };
    float* fb_all  = (float*)alloc((size_t)3 * EPAD * 4);
    float* c2_all  = (float*)alloc((size_t)3 * CC * 4);
    float* lt_all  = (float*)alloc((size_t)3 * LL * 4);
    float* cb2_all = (float*)alloc((size_t)3 * CC * 4);
    __hip_bfloat16* qb      = (__hip_bfloat16*)alloc((size_t)MM * CC * 2);
    __hip_bfloat16* W1T_all = (__hip_bfloat16*)alloc((size_t)3 * EPAD * CC * 2);
    __hip_bfloat16* W2T_all = (__hip_bfloat16*)alloc((size_t)3 * CC * EPAD * 2);
    __hip_bfloat16* Hb      = (__hip_bfloat16*)alloc((size_t)MM * 3 * EPAD * 2);
    __hip_bfloat16* rkvb    = (__hip_bfloat16*)alloc((size_t)3 * MM * CC * 2);   // r,k,v bf16
    __hip_bfloat16* gadbuf  = (__hip_bfloat16*)alloc((size_t)3 * MM * CC * 2);
    __hip_bfloat16* gbuf = gadbuf;
    __hip_bfloat16* abuf = gadbuf + (size_t)MM * CC;
    __hip_bfloat16* dbuf = gadbuf + (size_t)2 * MM * CC;
    __hip_bfloat16* rbuf = rkvb;
    __hip_bfloat16* kbuf = rkvb + (size_t)MM * CC;
    __hip_bfloat16* vbuf = rkvb + (size_t)2 * MM * CC;
    // time-multiplexed tenants of the rkvb arena (48 MB):
    float*          pp      = (float*)rkvb;                                 // fold partials (dies before AT/BT)
    __hip_bfloat16* AT_all  = (__hip_bfloat16*)((char*)rkvb + (1 << 18));   // LoRA A^T
    __hip_bfloat16* BT_all  = (__hip_bfloat16*)((char*)rkvb + (1 << 18) + 786432);
    __hip_bfloat16* oW1T    = (__hip_bfloat16*)rkvb;                        // written after recurrence
    __hip_bfloat16* oW2T    = (__hip_bfloat16*)((char*)rkvb + 4194304);
    __hip_bfloat16* tgad    = Hb;
    __hip_bfloat16* robuf   = (__hip_bfloat16*)out;                          // recurrence out (bf16 in d_out scratch)

    const dim3 blk(256);
    const dim3 tblk(32, 8);

    gather3<<<dim3(4), blk, 0, stream>>>(rb2, kb2, vb2, cb2_all);

    fold_pass1_z<<<dim3(20, 16, 3), blk, 0, stream>>>(mu_r, mu_k, mu_v, rW1, kW1, vW1,
                                                      pp, EE, EE, EPAD, 16 * EPAD);
    fold_pass2_z<<<dim3(5, 1, 3), blk, 0, stream>>>(pp, rb1, kb1, vb1, fb_all,
                                                    16, EPAD, 16 * EPAD, EE, EPAD, EPAD);
    fold_pass1_z<<<dim3(2, 16, 3), blk, 0, stream>>>(mu_g, mu_a, mu_d, gA, aA, dA,
                                                     pp, LL, LL, EPAD, 16 * EPAD);
    fold_pass2_z<<<dim3(1, 1, 3), dim3(128), 0, stream>>>(pp, nullptr, nullptr, nullptr, lt_all,
                                                          16, EPAD, 16 * EPAD, LL, LL, LL);
    fold_pass1_z<<<dim3(16, 2, 3), blk, 0, stream>>>(lt_all, lt_all + LL, lt_all + 2 * LL, gB, aB, dB,
                                                     pp, CC, CC, EPAD, 16 * EPAD);
    fold_pass2_z<<<dim3(4, 1, 3), blk, 0, stream>>>(pp, nullptr, ab, db, c2_all,
                                                    2, EPAD, 16 * EPAD, CC, CC, CC);

    transpose_cast_z<<<dim3(32, 40, 3), tblk, 0, stream>>>(rW1, kW1, vW1, W1T_all,
                                                           (size_t)EPAD * CC, CC, EE, CC, EPAD);
    transpose_cast_z<<<dim3(40, 32, 3), tblk, 0, stream>>>(rW2, kW2, vW2, W2T_all,
                                                           (size_t)CC * EPAD, EE, CC, EPAD, CC);
    transpose_cast_z<<<dim3(32, 4, 3), tblk, 0, stream>>>(gA, aA, dA, AT_all,
                                                          (size_t)LL * CC, CC, LL, CC, LL);
    transpose_cast_z<<<dim3(4, 32, 3), tblk, 0, stream>>>(gB, aB, dB, BT_all,
                                                          (size_t)CC * LL, LL, CC, LL, CC);

    cast_f32_bf16<<<dim3(MM * CC / 4 / 256), blk, 0, stream>>>(q, qb, MM * CC / 4);

    gemm_mfma<0,-1,1,0><<<dim3(3, 64, 1), blk, 0, stream>>>(qb, AT_all, nullptr, tgad,
                                                            MM, 384, CC, CC, CC, 384, 0, 0, 0, 0);
    gemm_mfma<2,3,1,0><<<dim3(8, 64, 3), blk, 0, stream>>>(tgad, BT_all, c2_all, gadbuf,
                                                           MM, CC, LL, 384, LL, CC,
                                                           LL, (size_t)CC * LL, CC, (size_t)MM * CC);

    gemm_mfma<1,-1,1,0><<<dim3(30, 64, 1), blk, 0, stream>>>(qb, W1T_all, fb_all, Hb,
                                                             MM, 3 * EPAD, CC, CC, CC, 3 * EPAD, 0, 0, 0, 0);
    gemm_mfma<0,-1,1,0><<<dim3(8, 64, 3), blk, 0, stream>>>(Hb, W2T_all, cb2_all, rkvb,
                                                            MM, CC, EPAD, 3 * EPAD, EPAD, CC,
                                                            EPAD, (size_t)CC * EPAD, CC, (size_t)MM * CC);

    recurrence_chunked<<<dim3(BB * HH * NSEG), dim3(512), 0, stream>>>(
        kbuf, abuf, dbuf, vbuf, rbuf, rem_mult, iclr_mix, bonus_mult, robuf);

    transpose_cast_z<<<dim3(32, 40, 1), tblk, 0, stream>>>(oW1, oW1, oW1, oW1T,
                                                           0, CC, EE, CC, EPAD);
    transpose_cast_z<<<dim3(40, 32, 1), tblk, 0, stream>>>(oW2, oW2, oW2, oW2T,
                                                           0, EE, CC, EPAD, CC);

    ln_gate_kernel<<<dim3(MM), blk, 0, stream>>>(robuf, gbuf, ln_g, ln_b, qb);

    gemm_mfma<1,-1,1,1><<<dim3(10, 64, 1), blk, 0, stream>>>(qb, oW1T, ob1, Hb,
                                                             MM, EE, CC, CC, CC, EPAD, 0, 0, 0, 0);
    gemm_mfma<0,-1,0,0><<<dim3(8, 64, 1), blk, 0, stream>>>(Hb, oW2T, ob2, out,
                                                            MM, CC, EPAD, EPAD, EPAD, CC, 0, 0, 0, 0);
}

// Round 19
// 860.217 us; speedup vs baseline: 1.0034x; 1.0034x over previous
//
#include <hip/hip_runtime.h>
#include <hip/hip_bf16.h>
#include <math.h>

// LinearAttentionLayerOptimized: B=4, T=2048, C=1024, H=16, N=64, L=128, E=1228
// Round 18: round-16 base + zero-tile skips ONLY (AT/BM/P2t/GRt; wave-uniform
// branch, static unrolled inner loops, zeros still written). Round 17's
// phase6a runtime-bound truncation REVERTED (it broke the unroll schedule and
// skewed stores -> write-combining loss; r17 counters: VALUBusy 38->32,
// WRITE 16.4->36MB). phase6a = round 16's exact static form.

#define BB 4
#define TT 2048
#define CC 1024
#define HH 16
#define NN 64
#define LL 128
#define EE 1228
#define EPAD 1280
#define MM (BB*TT)          // 8192 rows
#define TCH 32
#define NSEG 4
#define WARMCH 2            // 64 warm-up steps; decay<=0.82 -> ~3e-6
#define DECAY_C_F 0.7408182206817179f

typedef __attribute__((ext_vector_type(8))) short s16x8;
typedef __attribute__((ext_vector_type(4))) float f32x4;

#define GLOAD_LDS16(gp, lp) \
    __builtin_amdgcn_global_load_lds((const __attribute__((address_space(1))) void*)(gp), \
                                     (__attribute__((address_space(3))) void*)(lp), 16, 0, 0)

__device__ __forceinline__ float fast_sigmoid(float w) {
    return __fdividef(1.0f, 1.0f + __expf(-w));
}
// tanh-form gelu: x*sigma(1.59576912*x*(1+0.044715x^2))
__device__ __forceinline__ float fast_gelu(float x) {
    float x2 = x * x;
    float w = 1.59576912f * x * fmaf(0.044715f, x2, 1.0f);
    return x * fast_sigmoid(w);
}
__device__ __forceinline__ float fast_decay(float x) {
    float t = fmaf(2.0f, fast_sigmoid(2.0f * x), -1.0f);   // tanh(x)
    float sg = fast_sigmoid(t);
    return __expf(-DECAY_C_F * sg);
}

// ---------------- z-batched two-pass bias folds ----------------
__global__ __launch_bounds__(256) void fold_pass1_z(
    const float* __restrict__ mu0, const float* __restrict__ mu1, const float* __restrict__ mu2,
    const float* __restrict__ W0,  const float* __restrict__ W1_, const float* __restrict__ W2_,
    float* __restrict__ partial, int ldW, int E, int ldP, int pslice) {
    const float* mu = blockIdx.z == 0 ? mu0 : (blockIdx.z == 1 ? mu1 : mu2);
    const float* W  = blockIdx.z == 0 ? W0  : (blockIdx.z == 1 ? W1_ : W2_);
    partial += (size_t)blockIdx.z * pslice;
    const int l = threadIdx.x & 63;
    const int e = blockIdx.x * 64 + l;
    const int pg = threadIdx.x >> 6;
    const int c0 = blockIdx.y * 64;
    float s = 0.f;
    if (e < E)
        for (int c = c0 + pg; c < c0 + 64; c += 4) s += mu[c] * W[(size_t)c * ldW + e];
    __shared__ float red[4][64];
    red[pg][l] = s;
    __syncthreads();
    if (pg == 0 && e < E)
        partial[(size_t)blockIdx.y * ldP + e] = red[0][l] + red[1][l] + red[2][l] + red[3][l];
}

__global__ void fold_pass2_z(const float* __restrict__ partial,
                             const float* b0, const float* b1, const float* b2,
                             float* __restrict__ outv,
                             int P, int ldP, int pslice, int E, int Epad, int oslice) {
    const float* bias = blockIdx.z == 0 ? b0 : (blockIdx.z == 1 ? b1 : b2);
    partial += (size_t)blockIdx.z * pslice;
    outv    += (size_t)blockIdx.z * oslice;
    int e = blockIdx.x * blockDim.x + threadIdx.x;
    if (e >= Epad) return;
    float s = 0.f;
    if (e < E) {
        s = bias ? bias[e] : 0.f;
        for (int p = 0; p < P; ++p) s += partial[(size_t)p * ldP + e];
    }
    outv[e] = s;
}

// gather 3 bias vectors into one contiguous [3][CC] buffer
__global__ void gather3(const float* __restrict__ a, const float* __restrict__ b,
                        const float* __restrict__ c, float* __restrict__ o) {
    int i = blockIdx.x * blockDim.x + threadIdx.x;
    if (i < CC) { o[i] = a[i]; o[CC + i] = b[i]; o[2 * CC + i] = c[i]; }
}

// ---------------- cast / z-batched transpose-cast ----------------
__global__ void cast_f32_bf16(const float* __restrict__ in, __hip_bfloat16* __restrict__ out, int n4) {
    int i = blockIdx.x * blockDim.x + threadIdx.x;
    if (i >= n4) return;
    float4 v = ((const float4*)in)[i];
    __hip_bfloat16 o[4] = {__float2bfloat16(v.x), __float2bfloat16(v.y),
                           __float2bfloat16(v.z), __float2bfloat16(v.w)};
    *(ulong1*)&out[i * 4] = *(ulong1*)o;
}

__global__ void transpose_cast_z(const float* s0, const float* s1, const float* s2,
                                 __hip_bfloat16* __restrict__ outT, size_t dslice,
                                 int Rin, int Cin, int Rpad, int Cpad) {
    const float* in = blockIdx.z == 0 ? s0 : (blockIdx.z == 1 ? s1 : s2);
    outT += (size_t)blockIdx.z * dslice;
    __shared__ float t[32][33];
    const int r0 = blockIdx.x * 32, c0 = blockIdx.y * 32;
    const int tx = threadIdx.x, ty = threadIdx.y;   // 32 x 8
    #pragma unroll
    for (int j = 0; j < 4; ++j) {
        int r = r0 + ty + j * 8, c = c0 + tx;
        t[ty + j * 8][tx] = (r < Rin && c < Cin) ? in[(size_t)r * Cin + c] : 0.f;
    }
    __syncthreads();
    #pragma unroll
    for (int j = 0; j < 4; ++j) {
        int c = c0 + ty + j * 8, r = r0 + tx;
        if (c < Cpad && r < Rpad) outT[(size_t)c * Rpad + r] = __float2bfloat16(t[tx][ty + j * 8]);
    }
}

// ---------------- bf16 MFMA GEMM, BK=64 (z-batched, per-z activation) ----------------
template<int ACT, int ACTZ2, int OBF, int PADZ>
__global__ __launch_bounds__(256) void gemm_mfma(const __hip_bfloat16* __restrict__ A,
                                                 const __hip_bfloat16* __restrict__ Bt,
                                                 const float* __restrict__ bias,
                                                 void* __restrict__ Cptr,
                                                 int M, int N, int K,
                                                 int ldA, int ldB, int ldC,
                                                 size_t zA, size_t zB, size_t zBias, size_t zC) {
    __shared__ __hip_bfloat16 As[128 * 64];   // 16 KB
    __shared__ __hip_bfloat16 Bs[128 * 64];   // 16 KB
    const int tid = threadIdx.x;
    const int wid = tid >> 6, lane = tid & 63;
    const int wm = wid >> 1, wn = wid & 1;
    const int bm = blockIdx.y * 128, bn = blockIdx.x * 128;
    A  += (size_t)blockIdx.z * zA;
    Bt += (size_t)blockIdx.z * zB;
    if (bias) bias += (size_t)blockIdx.z * zBias;
    const size_t zc = (size_t)blockIdx.z * zC;
    const int act = (ACTZ2 >= 0 && blockIdx.z == 2) ? ACTZ2 : ACT;

    const __hip_bfloat16* srcA[4];
    const __hip_bfloat16* srcB[4];
    #pragma unroll
    for (int i = 0; i < 4; ++i) {
        int off = (wid * 4 + i) * 1024 + lane * 16;
        int r = off >> 7;            // 128 B rows
        int c = (off >> 4) & 7;      // chunk position
        int cs = c ^ (r & 7);        // source chunk
        srcA[i] = A  + (size_t)(bm + r) * ldA + cs * 8;
        srcB[i] = Bt + (size_t)(bn + r) * ldB + cs * 8;
    }

    f32x4 acc[4][4];
    #pragma unroll
    for (int i = 0; i < 4; ++i)
        #pragma unroll
        for (int j = 0; j < 4; ++j) acc[i][j] = (f32x4){0.f, 0.f, 0.f, 0.f};

    const int ra = wm * 64 + (lane & 15);
    const int rb = wn * 64 + (lane & 15);

    for (int k0 = 0; k0 < K; k0 += 64) {
        #pragma unroll
        for (int i = 0; i < 4; ++i) {
            GLOAD_LDS16(srcA[i] + k0, (char*)As + (wid * 4 + i) * 1024);
            GLOAD_LDS16(srcB[i] + k0, (char*)Bs + (wid * 4 + i) * 1024);
        }
        __syncthreads();
        #pragma unroll
        for (int h = 0; h < 2; ++h) {
            s16x8 af[4], bfr[4];
            const int kc = (lane >> 4) + h * 4;
            #pragma unroll
            for (int mi = 0; mi < 4; ++mi) {
                int r = ra + mi * 16;
                af[mi] = *(const s16x8*)((const char*)As + r * 128 + (kc ^ (r & 7)) * 16);
            }
            #pragma unroll
            for (int ni = 0; ni < 4; ++ni) {
                int r = rb + ni * 16;
                bfr[ni] = *(const s16x8*)((const char*)Bs + r * 128 + (kc ^ (r & 7)) * 16);
            }
            #pragma unroll
            for (int mi = 0; mi < 4; ++mi)
                #pragma unroll
                for (int ni = 0; ni < 4; ++ni)
                    acc[mi][ni] = __builtin_amdgcn_mfma_f32_16x16x32_bf16(af[mi], bfr[ni], acc[mi][ni], 0, 0, 0);
        }
        __syncthreads();
    }

    #pragma unroll
    for (int ni = 0; ni < 4; ++ni) {
        const int col = bn + wn * 64 + ni * 16 + (lane & 15);
        const bool valid = (col < N);
        const float bc = (valid && bias) ? bias[col] : 0.f;
        #pragma unroll
        for (int mi = 0; mi < 4; ++mi) {
            #pragma unroll
            for (int reg = 0; reg < 4; ++reg) {
                const int row = bm + wm * 64 + mi * 16 + (lane >> 4) * 4 + reg;
                float y = 0.f;
                if (valid) {
                    float x = acc[mi][ni][reg] + bc;
                    if (act == 1)      y = fast_gelu(x);
                    else if (act == 2) y = fast_sigmoid(x);
                    else if (act == 3) y = fast_decay(x);
                    else               y = x;
                }
                if (valid || PADZ) {
                    if (OBF) ((__hip_bfloat16*)Cptr)[zc + (size_t)row * ldC + col] = __float2bfloat16(y);
                    else     ((float*)Cptr)[zc + (size_t)row * ldC + col] = y;
                }
            }
        }
    }
}

// ---------------- segment-parallel chunked recurrence (512 threads, 8 waves) ----------------
#define P_T0(i,j)   pool[0     + (i)*68 + (j)]
#define P_WT(i,j)   pool[4352  + (i)*68 + (j)]
#define P_KP(i,j)   pool[6528  + (i)*68 + (j)]
#define P_P2t(i,j)  pool[6528  + (i)*36 + (j)]   // aliases KP (dead after phase2; 6b uses KPT)
#define P_NU(i,j)   pool[8704  + (i)*68 + (j)]
#define P_GRt(i,j)  pool[8704  + (i)*36 + (j)]   // aliases NU (dead after phase2; 6b uses NUT)
#define P_RKM(i,j)  pool[10880 + (i)*68 + (j)]
#define P_RRM(i,j)  pool[13056 + (i)*68 + (j)]
#define P_GM(i,j)   pool[15232 + (i)*68 + (j)]
// hole @17408 (was GMT - deleted)
#define P_KPT(i,j)  pool[19712 + (i)*36 + (j)]
#define P_NUT(i,j)  pool[22016 + (i)*36 + (j)]
// hole @24320 (was RKMT - deleted)
#define P_DCT(i,j)  pool[26624 + (i)*36 + (j)]
#define P_AT(i,j)   pool[28928 + (i)*36 + (j)]
#define P_BM(i,j)   pool[30080 + (i)*36 + (j)]
#define P_SEG(i,j)  pool[31232 + (i)*64 + (j)]
#define LD4(expr)   (*(const float4*)&(expr))
#define FMA4(acc, s, v) { (acc).x = fmaf((s), (v).x, (acc).x); (acc).y = fmaf((s), (v).y, (acc).y); \
                          (acc).z = fmaf((s), (v).z, (acc).z); (acc).w = fmaf((s), (v).w, (acc).w); }
#define DOT4(a, b) ((a).x*(b).x + (a).y*(b).y + (a).z*(b).z + (a).w*(b).w)

__global__ __launch_bounds__(512) void recurrence_chunked(
    const __hip_bfloat16* __restrict__ kbuf, const __hip_bfloat16* __restrict__ iclr,
    const __hip_bfloat16* __restrict__ dbuf, const __hip_bfloat16* __restrict__ vbuf,
    const __hip_bfloat16* __restrict__ rbuf,
    const float* __restrict__ rem_mult, const float* __restrict__ iclr_mix,
    const float* __restrict__ bonus_mult, __hip_bfloat16* __restrict__ outb) {
    __shared__ float pool[31488];   // 123 KB
    const int bh = blockIdx.x & 63, seg = blockIdx.x >> 6;
    const int b = bh >> 4, h = bh & 15;
    const int tid = threadIdx.x, lane = tid & 63, wid = tid >> 6;
    const size_t gbase = ((size_t)b * TT) * CC + (size_t)h * NN;

    for (int i = tid; i < 4352; i += 512) pool[i] = 0.f;   // T0 = 0 at segment start
    const int c0 = tid & 63;
    const float remc = rem_mult[h * NN + c0];
    const float mixc = iclr_mix[h * NN + c0];
    __syncthreads();

    // stagger: outputs {18,16,15,15}, warm-up 2 chunks for seg>0 -> max 18 chunks/block
    const int cout0 = (seg == 0) ? 0 : (seg == 1) ? 18 : (seg == 2) ? 34 : 49;
    const int lenq  = (seg == 0) ? 18 : (seg == 1) ? 16 : 15;
    const int ce    = cout0 + lenq;
    const int cb    = (seg == 0) ? 0 : cout0 - WARMCH;

    for (int chk = cb; chk < ce; ++chk) {
        const bool emit = (chk >= cout0);
        const int tg0 = chk * TCH;
        // ---- load & elementwise (bf16 inputs) ----
        #pragma unroll
        for (int i = 0; i < 4; ++i) {
            int idx = tid + 512 * i;
            int t = idx >> 6, c = idx & 63;
            size_t off = gbase + (size_t)(tg0 + t) * CC + c;
            float kx = __bfloat162float(kbuf[off]);
            float ax = __bfloat162float(iclr[off]);
            float rk = kx * (1.f + (ax - 1.f) * mixc);
            P_WT(t, c) = ax;
            P_KP(t, c) = kx * remc;
            P_RKM(t, c) = rk;
            P_NU(t, c) = __bfloat162float(vbuf[off]);
            if (emit) P_RRM(t, c) = __bfloat162float(rbuf[off]);
            P_DCT(c, t) = __bfloat162float(dbuf[off]);
        }
        __syncthreads();
        // ---- merged: row norms (all waves) + cumprod part1 (tid<256) ----
        #pragma unroll
        for (int rr = 0; rr < 4; ++rr) {
            int t = wid + rr * 8;
            float v = P_KP(t, lane);
            float ss = v * v;
            #pragma unroll
            for (int s = 32; s; s >>= 1) ss += __shfl_xor(ss, s);
            float kn = v / fmaxf(sqrtf(ss), 1e-12f);
            P_KP(t, lane) = kn;
            P_WT(t, lane) = P_WT(t, lane) * kn;
        }
        float lc[8];
        const int ccs = tid & 63, sgm = tid >> 6, t0s = (sgm & 3) * 8;
        if (tid < 256) {
            float pp_ = 1.f;
            #pragma unroll
            for (int j = 0; j < 8; ++j) { pp_ *= P_DCT(ccs, t0s + j); lc[j] = pp_; }
            P_SEG(sgm, ccs) = pp_;
        }
        __syncthreads();
        // ---- cumprod part2 + scaled quantities (256 threads) ----
        if (tid < 256) {
            float m = 1.f;
            for (int s = 0; s < sgm; ++s) m *= P_SEG(s, ccs);
            float dcprev = m;
            #pragma unroll
            for (int j = 0; j < 8; ++j) {
                int t = t0s + j;
                float dcur = m * lc[j];
                P_WT(t, ccs) *= dcprev;
                float inv = 1.f / dcur;
                float kap = P_KP(t, ccs) * inv; P_KP(t, ccs) = kap; P_KPT(ccs, t) = kap;
                float nu  = P_NU(t, ccs) * inv; P_NU(t, ccs) = nu;  P_NUT(ccs, t) = nu;
                P_DCT(ccs, t) = dcur;
                dcprev = dcur;
            }
        }
        __syncthreads();
        // ---- phase2: AT (2 tiles/wave) + BM (2 tiles/wave) + GM1 slab (1/wave) ----
        // Zero-tile skip: s-block > t-block tiles are entirely zero (wave-uniform,
        // static inner loops preserved, zeros still written).
        #pragma unroll
        for (int u = 0; u < 2; ++u) {
            const int at = wid * 2 + u;   // 0..15
            const int sb = at >> 2, tb = at & 3;
            const int s = sb * 8 + (lane >> 3), t = tb * 8 + (lane & 7);
            if (sb > tb) { P_AT(s, t) = 0.f; continue; }
            float acc = 0.f;
            #pragma unroll
            for (int kc = 0; kc < 16; ++kc) {
                float4 a = LD4(P_KP(s, kc * 4));
                float4 bb = LD4(P_WT(t, kc * 4));
                acc += DOT4(a, bb);
            }
            P_AT(s, t) = (s < t) ? acc : 0.f;
        }
        #pragma unroll
        for (int u = 0; u < 2; ++u) {
            const int bt = wid * 2 + u;   // 0..15
            const int tb = bt >> 2, sb = bt & 3;
            const int t = tb * 8 + (lane >> 3), s = sb * 8 + (lane & 7);
            if (sb > tb) { P_BM(t, s) = 0.f; continue; }
            float acc = 0.f;
            #pragma unroll
            for (int kc = 0; kc < 16; ++kc) {
                float4 a = LD4(P_WT(t, kc * 4));
                float4 bb = LD4(P_NU(s, kc * 4));
                acc += DOT4(a, bb);
            }
            P_BM(t, s) = (s < t) ? acc : 0.f;
        }
        {   // GM1: wave owns GM rows [wid*4, wid*4+4) x all 64 q
            const int t = wid * 4 + (lane >> 4);
            const int q4 = (lane & 15) * 4;
            float4 acc = {0.f, 0.f, 0.f, 0.f};
            #pragma unroll
            for (int j4 = 0; j4 < 16; ++j4) {
                float4 w4 = LD4(P_WT(t, j4 * 4));
                float4 ta = LD4(P_T0(j4 * 4 + 0, q4));
                float4 tb = LD4(P_T0(j4 * 4 + 1, q4));
                float4 tc = LD4(P_T0(j4 * 4 + 2, q4));
                float4 td = LD4(P_T0(j4 * 4 + 3, q4));
                FMA4(acc, w4.x, ta); FMA4(acc, w4.y, tb);
                FMA4(acc, w4.z, tc); FMA4(acc, w4.w, td);
            }
            *(float4*)&P_GM(t, q4) = acc;
        }
        __syncthreads();
        // ---- phase3: GM += BM . RKM ----
        {
            const int t = wid * 4 + (lane >> 4);
            const int q4 = (lane & 15) * 4;
            float4 acc = {0.f, 0.f, 0.f, 0.f};
            #pragma unroll
            for (int s4 = 0; s4 < 8; ++s4) {
                float4 bm4 = LD4(P_BM(t, s4 * 4));
                float4 ra = LD4(P_RKM(s4 * 4 + 0, q4));
                float4 rb = LD4(P_RKM(s4 * 4 + 1, q4));
                float4 rc = LD4(P_RKM(s4 * 4 + 2, q4));
                float4 rd = LD4(P_RKM(s4 * 4 + 3, q4));
                FMA4(acc, bm4.x, ra); FMA4(acc, bm4.y, rb);
                FMA4(acc, bm4.z, rc); FMA4(acc, bm4.w, rd);
            }
            float4 g = LD4(P_GM(t, q4));
            g.x += acc.x; g.y += acc.y; g.z += acc.z; g.w += acc.w;
            *(float4*)&P_GM(t, q4) = g;
        }
        __syncthreads();
        // ---- phase4: wave0 forward substitution || waves1-7: P2t (emit only) ----
        if (wid == 0) {
            float g[32];
            #pragma unroll
            for (int t = 0; t < 32; ++t) g[t] = P_GM(t, lane);
            #pragma unroll
            for (int s = 0; s < 31; ++s) {
                #pragma unroll
                for (int t = s + 1; t < 32; ++t) g[t] -= P_AT(s, t) * g[s];
            }
            #pragma unroll
            for (int t = 0; t < 32; ++t) P_GM(t, lane) = g[t];
        } else if (emit) {
            for (int tile = wid - 1; tile < 16; tile += 7) {
                const int tb = tile >> 2, sb = tile & 3;
                int t = tb * 8 + (lane >> 3), s = sb * 8 + (lane & 7);
                if (sb > tb) { P_P2t(t, s) = 0.f; continue; }   // zero tile (s>t)
                float acc = 0.f;
                #pragma unroll
                for (int kc = 0; kc < 16; ++kc) {
                    float4 a = LD4(P_RRM(t, kc * 4));
                    float4 bb = LD4(P_RKM(s, kc * 4));
                    acc += DOT4(a, bb);
                }
                P_P2t(t, s) = (s <= t) ? acc : 0.f;
            }
        }
        __syncthreads();
        if (emit) {
            // ---- phase5: GRt[t][s] = g_s . r_t (16 tiles; skip zero tiles) ----
            for (int tile = wid; tile < 16; tile += 8) {
                const int tb = tile >> 2, sb = tile & 3;
                int t = tb * 8 + (lane >> 3), s = sb * 8 + (lane & 7);
                if (sb > tb) { P_GRt(t, s) = 0.f; continue; }
                float acc = 0.f;
                #pragma unroll
                for (int kc = 0; kc < 16; ++kc) {
                    float4 a = LD4(P_RRM(t, kc * 4));
                    float4 bb = LD4(P_GM(s, kc * 4));
                    acc += DOT4(a, bb);
                }
                P_GRt(t, s) = (s <= t) ? acc : 0.f;
            }
            __syncthreads();
            // ---- phase6a: outputs (32 tiles; round-16 static form) ----
            for (int tile = wid; tile < 32; tile += 8) {
                int i = (tile >> 2) * 8 + (lane >> 3), t = (tile & 3) * 8 + (lane & 7);
                float a1 = 0.f, a2 = 0.f, a3 = 0.f;
                #pragma unroll
                for (int j4 = 0; j4 < 16; ++j4) {
                    float4 a = LD4(P_T0(i, j4 * 4));
                    float4 bb = LD4(P_RRM(t, j4 * 4));
                    a1 += DOT4(a, bb);
                }
                #pragma unroll
                for (int s4 = 0; s4 < 8; ++s4) {
                    float4 a = LD4(P_NUT(i, s4 * 4));
                    float4 bb = LD4(P_P2t(t, s4 * 4));
                    a2 += DOT4(a, bb);
                    float4 c = LD4(P_KPT(i, s4 * 4));
                    float4 d = LD4(P_GRt(t, s4 * 4));
                    a3 += DOT4(c, d);
                }
                float diag = 0.2f * bonus_mult[h * NN + i] * P_NUT(i, t) * P_P2t(t, t);
                outb[gbase + (size_t)(tg0 + t) * CC + i] =
                    __float2bfloat16(P_DCT(i, t) * (a1 + a2 + diag - a3));
            }
            __syncthreads();
        }
        // ---- phase6b: T0 <- dc_end * (T0 - Kap^T G + Nu^T RK) (de-transposed slabs) ----
        #pragma unroll
        for (int u = 0; u < 2; ++u) {
            const int m = wid * 2 + u;                       // 0..15
            const int pr = (m & 7) * 8 + (lane >> 3);        // 0..63
            const int q4 = (m >> 3) * 32 + (lane & 7) * 4;   // 0..60
            float4 a1 = {0.f, 0.f, 0.f, 0.f}, a2 = {0.f, 0.f, 0.f, 0.f};
            #pragma unroll
            for (int s = 0; s < 32; ++s) {
                const float kp = P_KPT(pr, s);
                const float nu = P_NUT(pr, s);
                float4 g4 = LD4(P_GM(s, q4));
                float4 rk4 = LD4(P_RKM(s, q4));
                FMA4(a1, kp, g4);
                FMA4(a2, nu, rk4);
            }
            const float dc = P_DCT(pr, 31);
            float4 t0 = LD4(P_T0(pr, q4));
            t0.x = dc * (t0.x - a1.x + a2.x);
            t0.y = dc * (t0.y - a1.y + a2.y);
            t0.z = dc * (t0.z - a1.z + a2.z);
            t0.w = dc * (t0.w - a1.w + a2.w);
            *(float4*)&P_T0(pr, q4) = t0;
        }
        __syncthreads();
    }
}

// ---------------- LayerNorm * gate (bf16 in/out) ----------------
__global__ __launch_bounds__(256) void ln_gate_kernel(const __hip_bfloat16* __restrict__ x,
                                                      const __hip_bfloat16* __restrict__ gate,
                                                      const float* __restrict__ g,
                                                      const float* __restrict__ bv,
                                                      __hip_bfloat16* __restrict__ y) {
    const int row = blockIdx.x;
    const __hip_bfloat16* xr = x + (size_t)row * CC;
    float v[4];
    float s = 0.f;
    #pragma unroll
    for (int j = 0; j < 4; ++j) { v[j] = __bfloat162float(xr[threadIdx.x + 256 * j]); s += v[j]; }
    __shared__ float red[4], red2[4];
    #pragma unroll
    for (int o = 32; o; o >>= 1) s += __shfl_xor(s, o);
    if ((threadIdx.x & 63) == 0) red[threadIdx.x >> 6] = s;
    __syncthreads();
    const float mean = (red[0] + red[1] + red[2] + red[3]) * (1.f / CC);
    float vs = 0.f;
    #pragma unroll
    for (int j = 0; j < 4; ++j) { float d = v[j] - mean; vs += d * d; }
    #pragma unroll
    for (int o = 32; o; o >>= 1) vs += __shfl_xor(vs, o);
    if ((threadIdx.x & 63) == 0) red2[threadIdx.x >> 6] = vs;
    __syncthreads();
    const float var = (red2[0] + red2[1] + red2[2] + red2[3]) * (1.f / CC);
    const float rstd = rsqrtf(var + 1e-6f);
    #pragma unroll
    for (int j = 0; j < 4; ++j) {
        const int cc = threadIdx.x + 256 * j;
        float o_ = (v[j] - mean) * rstd * g[cc] + bv[cc];
        float gt = __bfloat162float(gate[(size_t)row * CC + cc]);
        y[(size_t)row * CC + cc] = __float2bfloat16(o_ * gt);
    }
}

// ---------------- launch ----------------
extern "C" void kernel_launch(void* const* d_in, const int* in_sizes, int n_in,
                              void* d_out, int out_size, void* d_ws, size_t ws_size,
                              hipStream_t stream) {
    const float* q        = (const float*)d_in[0];
    const float* mu_r     = (const float*)d_in[4];
    const float* mu_k     = (const float*)d_in[5];
    const float* mu_v     = (const float*)d_in[6];
    const float* mu_g     = (const float*)d_in[7];
    const float* mu_a     = (const float*)d_in[8];
    const float* mu_d     = (const float*)d_in[9];
    const float* dA       = (const float*)d_in[10];
    const float* dB       = (const float*)d_in[11];
    const float* db       = (const float*)d_in[12];
    const float* aA       = (const float*)d_in[13];
    const float* aB       = (const float*)d_in[14];
    const float* ab       = (const float*)d_in[15];
    const float* gA       = (const float*)d_in[16];
    const float* gB       = (const float*)d_in[17];
    const float* rW1      = (const float*)d_in[18];
    const float* rb1      = (const float*)d_in[19];
    const float* rW2      = (const float*)d_in[20];
    const float* rb2      = (const float*)d_in[21];
    const float* kW1      = (const float*)d_in[22];
    const float* kb1      = (const float*)d_in[23];
    const float* kW2      = (const float*)d_in[24];
    const float* kb2      = (const float*)d_in[25];
    const float* vW1      = (const float*)d_in[26];
    const float* vb1      = (const float*)d_in[27];
    const float* vW2      = (const float*)d_in[28];
    const float* vb2      = (const float*)d_in[29];
    const float* oW1      = (const float*)d_in[30];
    const float* ob1      = (const float*)d_in[31];
    const float* oW2      = (const float*)d_in[32];
    const float* ob2      = (const float*)d_in[33];
    const float* rem_mult = (const float*)d_in[34];
    const float* iclr_mix = (const float*)d_in[35];
    const float* bonus_mult = (const float*)d_in[36];
    const float* ln_g     = (const float*)d_in[37];
    const float* ln_b     = (const float*)d_in[38];
    float* out = (float*)d_out;

    // ---- workspace arena (~220 MB) ----
    char* p = (char*)d_ws;
    auto alloc = [&](size_t bytes) { char* r = p; p += (bytes + 255) & ~(size_t)255; return r; };
    float* fb_all  = (float*)alloc((size_t)3 * EPAD * 4);
    float* c2_all  = (float*)alloc((size_t)3 * CC * 4);
    float* lt_all  = (float*)alloc((size_t)3 * LL * 4);
    float* cb2_all = (float*)alloc((size_t)3 * CC * 4);
    __hip_bfloat16* qb      = (__hip_bfloat16*)alloc((size_t)MM * CC * 2);
    __hip_bfloat16* W1T_all = (__hip_bfloat16*)alloc((size_t)3 * EPAD * CC * 2);
    __hip_bfloat16* W2T_all = (__hip_bfloat16*)alloc((size_t)3 * CC * EPAD * 2);
    __hip_bfloat16* Hb      = (__hip_bfloat16*)alloc((size_t)MM * 3 * EPAD * 2);
    __hip_bfloat16* rkvb    = (__hip_bfloat16*)alloc((size_t)3 * MM * CC * 2);   // r,k,v bf16
    __hip_bfloat16* gadbuf  = (__hip_bfloat16*)alloc((size_t)3 * MM * CC * 2);
    __hip_bfloat16* gbuf = gadbuf;
    __hip_bfloat16* abuf = gadbuf + (size_t)MM * CC;
    __hip_bfloat16* dbuf = gadbuf + (size_t)2 * MM * CC;
    __hip_bfloat16* rbuf = rkvb;
    __hip_bfloat16* kbuf = rkvb + (size_t)MM * CC;
    __hip_bfloat16* vbuf = rkvb + (size_t)2 * MM * CC;
    // time-multiplexed tenants of the rkvb arena (48 MB):
    float*          pp      = (float*)rkvb;                                 // fold partials (dies before AT/BT)
    __hip_bfloat16* AT_all  = (__hip_bfloat16*)((char*)rkvb + (1 << 18));   // LoRA A^T
    __hip_bfloat16* BT_all  = (__hip_bfloat16*)((char*)rkvb + (1 << 18) + 786432);
    __hip_bfloat16* oW1T    = (__hip_bfloat16*)rkvb;                        // written after recurrence
    __hip_bfloat16* oW2T    = (__hip_bfloat16*)((char*)rkvb + 4194304);
    __hip_bfloat16* tgad    = Hb;
    __hip_bfloat16* robuf   = (__hip_bfloat16*)out;                          // recurrence out (bf16 in d_out scratch)

    const dim3 blk(256);
    const dim3 tblk(32, 8);

    gather3<<<dim3(4), blk, 0, stream>>>(rb2, kb2, vb2, cb2_all);

    fold_pass1_z<<<dim3(20, 16, 3), blk, 0, stream>>>(mu_r, mu_k, mu_v, rW1, kW1, vW1,
                                                      pp, EE, EE, EPAD, 16 * EPAD);
    fold_pass2_z<<<dim3(5, 1, 3), blk, 0, stream>>>(pp, rb1, kb1, vb1, fb_all,
                                                    16, EPAD, 16 * EPAD, EE, EPAD, EPAD);
    fold_pass1_z<<<dim3(2, 16, 3), blk, 0, stream>>>(mu_g, mu_a, mu_d, gA, aA, dA,
                                                     pp, LL, LL, EPAD, 16 * EPAD);
    fold_pass2_z<<<dim3(1, 1, 3), dim3(128), 0, stream>>>(pp, nullptr, nullptr, nullptr, lt_all,
                                                          16, EPAD, 16 * EPAD, LL, LL, LL);
    fold_pass1_z<<<dim3(16, 2, 3), blk, 0, stream>>>(lt_all, lt_all + LL, lt_all + 2 * LL, gB, aB, dB,
                                                     pp, CC, CC, EPAD, 16 * EPAD);
    fold_pass2_z<<<dim3(4, 1, 3), blk, 0, stream>>>(pp, nullptr, ab, db, c2_all,
                                                    2, EPAD, 16 * EPAD, CC, CC, CC);

    transpose_cast_z<<<dim3(32, 40, 3), tblk, 0, stream>>>(rW1, kW1, vW1, W1T_all,
                                                           (size_t)EPAD * CC, CC, EE, CC, EPAD);
    transpose_cast_z<<<dim3(40, 32, 3), tblk, 0, stream>>>(rW2, kW2, vW2, W2T_all,
                                                           (size_t)CC * EPAD, EE, CC, EPAD, CC);
    transpose_cast_z<<<dim3(32, 4, 3), tblk, 0, stream>>>(gA, aA, dA, AT_all,
                                                          (size_t)LL * CC, CC, LL, CC, LL);
    transpose_cast_z<<<dim3(4, 32, 3), tblk, 0, stream>>>(gB, aB, dB, BT_all,
                                                          (size_t)CC * LL, LL, CC, LL, CC);

    cast_f32_bf16<<<dim3(MM * CC / 4 / 256), blk, 0, stream>>>(q, qb, MM * CC / 4);

    gemm_mfma<0,-1,1,0><<<dim3(3, 64, 1), blk, 0, stream>>>(qb, AT_all, nullptr, tgad,
                                                            MM, 384, CC, CC, CC, 384, 0, 0, 0, 0);
    gemm_mfma<2,3,1,0><<<dim3(8, 64, 3), blk, 0, stream>>>(tgad, BT_all, c2_all, gadbuf,
                                                           MM, CC, LL, 384, LL, CC,
                                                           LL, (size_t)CC * LL, CC, (size_t)MM * CC);

    gemm_mfma<1,-1,1,0><<<dim3(30, 64, 1), blk, 0, stream>>>(qb, W1T_all, fb_all, Hb,
                                                             MM, 3 * EPAD, CC, CC, CC, 3 * EPAD, 0, 0, 0, 0);
    gemm_mfma<0,-1,1,0><<<dim3(8, 64, 3), blk, 0, stream>>>(Hb, W2T_all, cb2_all, rkvb,
                                                            MM, CC, EPAD, 3 * EPAD, EPAD, CC,
                                                            EPAD, (size_t)CC * EPAD, CC, (size_t)MM * CC);

    recurrence_chunked<<<dim3(BB * HH * NSEG), dim3(512), 0, stream>>>(
        kbuf, abuf, dbuf, vbuf, rbuf, rem_mult, iclr_mix, bonus_mult, robuf);

    transpose_cast_z<<<dim3(32, 40, 1), tblk, 0, stream>>>(oW1, oW1, oW1, oW1T,
                                                           0, CC, EE, CC, EPAD);
    transpose_cast_z<<<dim3(40, 32, 1), tblk, 0, stream>>>(oW2, oW2, oW2, oW2T,
                                                           0, EE, CC, EPAD, CC);

    ln_gate_kernel<<<dim3(MM), blk, 0, stream>>>(robuf, gbuf, ln_g, ln_b, qb);

    gemm_mfma<1,-1,1,1><<<dim3(10, 64, 1), blk, 0, stream>>>(qb, oW1T, ob1, Hb,
                                                             MM, EE, CC, CC, CC, EPAD, 0, 0, 0, 0);
    gemm_mfma<0,-1,0,0><<<dim3(8, 64, 1), blk, 0, stream>>>(Hb, oW2T, ob2, out,
                                                            MM, CC, EPAD, EPAD, EPAD, CC, 0, 0, 0, 0);
}

// Round 20
// 858.638 us; speedup vs baseline: 1.0053x; 1.0018x over previous
//
#include <hip/hip_runtime.h>
#include <hip/hip_bf16.h>
#include <math.h>

// LinearAttentionLayerOptimized: B=4, T=2048, C=1024, H=16, N=64, L=128, E=1228
// Round 19 (FINAL): consolidation on round 16's byte-exact kernel — the
// empirically best configuration (862.0us, recurrence 437.5us, WRITE exactly
// 16.4MB). All four attempts to reduce the recurrence's LDS work (r10 quad,
// r11 staged writeback, r17 truncation, r18 tile skips) were nullified or
// reversed by L2 write-combining / schedule second-order effects.
// Structure: bf16-MFMA GEMMs (BK=64, XOR-swizzled LDS, fast transcendental
// epilogues), segment-parallel WY-transform recurrence (512 thr / 128 VGPR,
// Tc=32, stagger {18,16,15,15}, WARMCH=2, all bf16 I/O), fused LN*gate.

#define BB 4
#define TT 2048
#define CC 1024
#define HH 16
#define NN 64
#define LL 128
#define EE 1228
#define EPAD 1280
#define MM (BB*TT)          // 8192 rows
#define TCH 32
#define NSEG 4
#define WARMCH 2            // 64 warm-up steps; decay<=0.82 -> ~3e-6
#define DECAY_C_F 0.7408182206817179f

typedef __attribute__((ext_vector_type(8))) short s16x8;
typedef __attribute__((ext_vector_type(4))) float f32x4;

#define GLOAD_LDS16(gp, lp) \
    __builtin_amdgcn_global_load_lds((const __attribute__((address_space(1))) void*)(gp), \
                                     (__attribute__((address_space(3))) void*)(lp), 16, 0, 0)

__device__ __forceinline__ float fast_sigmoid(float w) {
    return __fdividef(1.0f, 1.0f + __expf(-w));
}
// tanh-form gelu: x*sigma(1.59576912*x*(1+0.044715x^2))
__device__ __forceinline__ float fast_gelu(float x) {
    float x2 = x * x;
    float w = 1.59576912f * x * fmaf(0.044715f, x2, 1.0f);
    return x * fast_sigmoid(w);
}
__device__ __forceinline__ float fast_decay(float x) {
    float t = fmaf(2.0f, fast_sigmoid(2.0f * x), -1.0f);   // tanh(x)
    float sg = fast_sigmoid(t);
    return __expf(-DECAY_C_F * sg);
}

// ---------------- z-batched two-pass bias folds ----------------
__global__ __launch_bounds__(256) void fold_pass1_z(
    const float* __restrict__ mu0, const float* __restrict__ mu1, const float* __restrict__ mu2,
    const float* __restrict__ W0,  const float* __restrict__ W1_, const float* __restrict__ W2_,
    float* __restrict__ partial, int ldW, int E, int ldP, int pslice) {
    const float* mu = blockIdx.z == 0 ? mu0 : (blockIdx.z == 1 ? mu1 : mu2);
    const float* W  = blockIdx.z == 0 ? W0  : (blockIdx.z == 1 ? W1_ : W2_);
    partial += (size_t)blockIdx.z * pslice;
    const int l = threadIdx.x & 63;
    const int e = blockIdx.x * 64 + l;
    const int pg = threadIdx.x >> 6;
    const int c0 = blockIdx.y * 64;
    float s = 0.f;
    if (e < E)
        for (int c = c0 + pg; c < c0 + 64; c += 4) s += mu[c] * W[(size_t)c * ldW + e];
    __shared__ float red[4][64];
    red[pg][l] = s;
    __syncthreads();
    if (pg == 0 && e < E)
        partial[(size_t)blockIdx.y * ldP + e] = red[0][l] + red[1][l] + red[2][l] + red[3][l];
}

__global__ void fold_pass2_z(const float* __restrict__ partial,
                             const float* b0, const float* b1, const float* b2,
                             float* __restrict__ outv,
                             int P, int ldP, int pslice, int E, int Epad, int oslice) {
    const float* bias = blockIdx.z == 0 ? b0 : (blockIdx.z == 1 ? b1 : b2);
    partial += (size_t)blockIdx.z * pslice;
    outv    += (size_t)blockIdx.z * oslice;
    int e = blockIdx.x * blockDim.x + threadIdx.x;
    if (e >= Epad) return;
    float s = 0.f;
    if (e < E) {
        s = bias ? bias[e] : 0.f;
        for (int p = 0; p < P; ++p) s += partial[(size_t)p * ldP + e];
    }
    outv[e] = s;
}

// gather 3 bias vectors into one contiguous [3][CC] buffer (replaces 3 memcpys)
__global__ void gather3(const float* __restrict__ a, const float* __restrict__ b,
                        const float* __restrict__ c, float* __restrict__ o) {
    int i = blockIdx.x * blockDim.x + threadIdx.x;
    if (i < CC) { o[i] = a[i]; o[CC + i] = b[i]; o[2 * CC + i] = c[i]; }
}

// ---------------- cast / z-batched transpose-cast ----------------
__global__ void cast_f32_bf16(const float* __restrict__ in, __hip_bfloat16* __restrict__ out, int n4) {
    int i = blockIdx.x * blockDim.x + threadIdx.x;
    if (i >= n4) return;
    float4 v = ((const float4*)in)[i];
    __hip_bfloat16 o[4] = {__float2bfloat16(v.x), __float2bfloat16(v.y),
                           __float2bfloat16(v.z), __float2bfloat16(v.w)};
    *(ulong1*)&out[i * 4] = *(ulong1*)o;
}

__global__ void transpose_cast_z(const float* s0, const float* s1, const float* s2,
                                 __hip_bfloat16* __restrict__ outT, size_t dslice,
                                 int Rin, int Cin, int Rpad, int Cpad) {
    const float* in = blockIdx.z == 0 ? s0 : (blockIdx.z == 1 ? s1 : s2);
    outT += (size_t)blockIdx.z * dslice;
    __shared__ float t[32][33];
    const int r0 = blockIdx.x * 32, c0 = blockIdx.y * 32;
    const int tx = threadIdx.x, ty = threadIdx.y;   // 32 x 8
    #pragma unroll
    for (int j = 0; j < 4; ++j) {
        int r = r0 + ty + j * 8, c = c0 + tx;
        t[ty + j * 8][tx] = (r < Rin && c < Cin) ? in[(size_t)r * Cin + c] : 0.f;
    }
    __syncthreads();
    #pragma unroll
    for (int j = 0; j < 4; ++j) {
        int c = c0 + ty + j * 8, r = r0 + tx;
        if (c < Cpad && r < Rpad) outT[(size_t)c * Rpad + r] = __float2bfloat16(t[tx][ty + j * 8]);
    }
}

// ---------------- bf16 MFMA GEMM, BK=64 (z-batched, per-z activation) ----------------
template<int ACT, int ACTZ2, int OBF, int PADZ>
__global__ __launch_bounds__(256) void gemm_mfma(const __hip_bfloat16* __restrict__ A,
                                                 const __hip_bfloat16* __restrict__ Bt,
                                                 const float* __restrict__ bias,
                                                 void* __restrict__ Cptr,
                                                 int M, int N, int K,
                                                 int ldA, int ldB, int ldC,
                                                 size_t zA, size_t zB, size_t zBias, size_t zC) {
    __shared__ __hip_bfloat16 As[128 * 64];   // 16 KB
    __shared__ __hip_bfloat16 Bs[128 * 64];   // 16 KB
    const int tid = threadIdx.x;
    const int wid = tid >> 6, lane = tid & 63;
    const int wm = wid >> 1, wn = wid & 1;
    const int bm = blockIdx.y * 128, bn = blockIdx.x * 128;
    A  += (size_t)blockIdx.z * zA;
    Bt += (size_t)blockIdx.z * zB;
    if (bias) bias += (size_t)blockIdx.z * zBias;
    const size_t zc = (size_t)blockIdx.z * zC;
    const int act = (ACTZ2 >= 0 && blockIdx.z == 2) ? ACTZ2 : ACT;

    const __hip_bfloat16* srcA[4];
    const __hip_bfloat16* srcB[4];
    #pragma unroll
    for (int i = 0; i < 4; ++i) {
        int off = (wid * 4 + i) * 1024 + lane * 16;
        int r = off >> 7;            // 128 B rows
        int c = (off >> 4) & 7;      // chunk position
        int cs = c ^ (r & 7);        // source chunk
        srcA[i] = A  + (size_t)(bm + r) * ldA + cs * 8;
        srcB[i] = Bt + (size_t)(bn + r) * ldB + cs * 8;
    }

    f32x4 acc[4][4];
    #pragma unroll
    for (int i = 0; i < 4; ++i)
        #pragma unroll
        for (int j = 0; j < 4; ++j) acc[i][j] = (f32x4){0.f, 0.f, 0.f, 0.f};

    const int ra = wm * 64 + (lane & 15);
    const int rb = wn * 64 + (lane & 15);

    for (int k0 = 0; k0 < K; k0 += 64) {
        #pragma unroll
        for (int i = 0; i < 4; ++i) {
            GLOAD_LDS16(srcA[i] + k0, (char*)As + (wid * 4 + i) * 1024);
            GLOAD_LDS16(srcB[i] + k0, (char*)Bs + (wid * 4 + i) * 1024);
        }
        __syncthreads();
        #pragma unroll
        for (int h = 0; h < 2; ++h) {
            s16x8 af[4], bfr[4];
            const int kc = (lane >> 4) + h * 4;
            #pragma unroll
            for (int mi = 0; mi < 4; ++mi) {
                int r = ra + mi * 16;
                af[mi] = *(const s16x8*)((const char*)As + r * 128 + (kc ^ (r & 7)) * 16);
            }
            #pragma unroll
            for (int ni = 0; ni < 4; ++ni) {
                int r = rb + ni * 16;
                bfr[ni] = *(const s16x8*)((const char*)Bs + r * 128 + (kc ^ (r & 7)) * 16);
            }
            #pragma unroll
            for (int mi = 0; mi < 4; ++mi)
                #pragma unroll
                for (int ni = 0; ni < 4; ++ni)
                    acc[mi][ni] = __builtin_amdgcn_mfma_f32_16x16x32_bf16(af[mi], bfr[ni], acc[mi][ni], 0, 0, 0);
        }
        __syncthreads();
    }

    #pragma unroll
    for (int ni = 0; ni < 4; ++ni) {
        const int col = bn + wn * 64 + ni * 16 + (lane & 15);
        const bool valid = (col < N);
        const float bc = (valid && bias) ? bias[col] : 0.f;
        #pragma unroll
        for (int mi = 0; mi < 4; ++mi) {
            #pragma unroll
            for (int reg = 0; reg < 4; ++reg) {
                const int row = bm + wm * 64 + mi * 16 + (lane >> 4) * 4 + reg;
                float y = 0.f;
                if (valid) {
                    float x = acc[mi][ni][reg] + bc;
                    if (act == 1)      y = fast_gelu(x);
                    else if (act == 2) y = fast_sigmoid(x);
                    else if (act == 3) y = fast_decay(x);
                    else               y = x;
                }
                if (valid || PADZ) {
                    if (OBF) ((__hip_bfloat16*)Cptr)[zc + (size_t)row * ldC + col] = __float2bfloat16(y);
                    else     ((float*)Cptr)[zc + (size_t)row * ldC + col] = y;
                }
            }
        }
    }
}

// ---------------- segment-parallel chunked recurrence (512 threads, 8 waves) ----------------
#define P_T0(i,j)   pool[0     + (i)*68 + (j)]
#define P_WT(i,j)   pool[4352  + (i)*68 + (j)]
#define P_KP(i,j)   pool[6528  + (i)*68 + (j)]
#define P_P2t(i,j)  pool[6528  + (i)*36 + (j)]   // aliases KP (dead after phase2; 6b uses KPT)
#define P_NU(i,j)   pool[8704  + (i)*68 + (j)]
#define P_GRt(i,j)  pool[8704  + (i)*36 + (j)]   // aliases NU (dead after phase2; 6b uses NUT)
#define P_RKM(i,j)  pool[10880 + (i)*68 + (j)]
#define P_RRM(i,j)  pool[13056 + (i)*68 + (j)]
#define P_GM(i,j)   pool[15232 + (i)*68 + (j)]
// hole @17408 (was GMT - deleted)
#define P_KPT(i,j)  pool[19712 + (i)*36 + (j)]
#define P_NUT(i,j)  pool[22016 + (i)*36 + (j)]
// hole @24320 (was RKMT - deleted)
#define P_DCT(i,j)  pool[26624 + (i)*36 + (j)]
#define P_AT(i,j)   pool[28928 + (i)*36 + (j)]
#define P_BM(i,j)   pool[30080 + (i)*36 + (j)]
#define P_SEG(i,j)  pool[31232 + (i)*64 + (j)]
#define LD4(expr)   (*(const float4*)&(expr))
#define FMA4(acc, s, v) { (acc).x = fmaf((s), (v).x, (acc).x); (acc).y = fmaf((s), (v).y, (acc).y); \
                          (acc).z = fmaf((s), (v).z, (acc).z); (acc).w = fmaf((s), (v).w, (acc).w); }
#define DOT4(a, b) ((a).x*(b).x + (a).y*(b).y + (a).z*(b).z + (a).w*(b).w)

__global__ __launch_bounds__(512) void recurrence_chunked(
    const __hip_bfloat16* __restrict__ kbuf, const __hip_bfloat16* __restrict__ iclr,
    const __hip_bfloat16* __restrict__ dbuf, const __hip_bfloat16* __restrict__ vbuf,
    const __hip_bfloat16* __restrict__ rbuf,
    const float* __restrict__ rem_mult, const float* __restrict__ iclr_mix,
    const float* __restrict__ bonus_mult, __hip_bfloat16* __restrict__ outb) {
    __shared__ float pool[31488];   // 123 KB
    const int bh = blockIdx.x & 63, seg = blockIdx.x >> 6;
    const int b = bh >> 4, h = bh & 15;
    const int tid = threadIdx.x, lane = tid & 63, wid = tid >> 6;
    const size_t gbase = ((size_t)b * TT) * CC + (size_t)h * NN;

    for (int i = tid; i < 4352; i += 512) pool[i] = 0.f;   // T0 = 0 at segment start
    const int c0 = tid & 63;
    const float remc = rem_mult[h * NN + c0];
    const float mixc = iclr_mix[h * NN + c0];
    __syncthreads();

    // stagger: outputs {18,16,15,15}, warm-up 2 chunks for seg>0 -> max 18 chunks/block
    const int cout0 = (seg == 0) ? 0 : (seg == 1) ? 18 : (seg == 2) ? 34 : 49;
    const int lenq  = (seg == 0) ? 18 : (seg == 1) ? 16 : 15;
    const int ce    = cout0 + lenq;
    const int cb    = (seg == 0) ? 0 : cout0 - WARMCH;

    for (int chk = cb; chk < ce; ++chk) {
        const bool emit = (chk >= cout0);
        const int tg0 = chk * TCH;
        // ---- load & elementwise (bf16 inputs) ----
        #pragma unroll
        for (int i = 0; i < 4; ++i) {
            int idx = tid + 512 * i;
            int t = idx >> 6, c = idx & 63;
            size_t off = gbase + (size_t)(tg0 + t) * CC + c;
            float kx = __bfloat162float(kbuf[off]);
            float ax = __bfloat162float(iclr[off]);
            float rk = kx * (1.f + (ax - 1.f) * mixc);
            P_WT(t, c) = ax;
            P_KP(t, c) = kx * remc;
            P_RKM(t, c) = rk;
            P_NU(t, c) = __bfloat162float(vbuf[off]);
            if (emit) P_RRM(t, c) = __bfloat162float(rbuf[off]);
            P_DCT(c, t) = __bfloat162float(dbuf[off]);
        }
        __syncthreads();
        // ---- merged: row norms (all waves) + cumprod part1 (tid<256) ----
        #pragma unroll
        for (int rr = 0; rr < 4; ++rr) {
            int t = wid + rr * 8;
            float v = P_KP(t, lane);
            float ss = v * v;
            #pragma unroll
            for (int s = 32; s; s >>= 1) ss += __shfl_xor(ss, s);
            float kn = v / fmaxf(sqrtf(ss), 1e-12f);
            P_KP(t, lane) = kn;
            P_WT(t, lane) = P_WT(t, lane) * kn;
        }
        float lc[8];
        const int ccs = tid & 63, sgm = tid >> 6, t0s = (sgm & 3) * 8;
        if (tid < 256) {
            float pp_ = 1.f;
            #pragma unroll
            for (int j = 0; j < 8; ++j) { pp_ *= P_DCT(ccs, t0s + j); lc[j] = pp_; }
            P_SEG(sgm, ccs) = pp_;
        }
        __syncthreads();
        // ---- cumprod part2 + scaled quantities (256 threads) ----
        if (tid < 256) {
            float m = 1.f;
            for (int s = 0; s < sgm; ++s) m *= P_SEG(s, ccs);
            float dcprev = m;
            #pragma unroll
            for (int j = 0; j < 8; ++j) {
                int t = t0s + j;
                float dcur = m * lc[j];
                P_WT(t, ccs) *= dcprev;
                float inv = 1.f / dcur;
                float kap = P_KP(t, ccs) * inv; P_KP(t, ccs) = kap; P_KPT(ccs, t) = kap;
                float nu  = P_NU(t, ccs) * inv; P_NU(t, ccs) = nu;  P_NUT(ccs, t) = nu;
                P_DCT(ccs, t) = dcur;
                dcprev = dcur;
            }
        }
        __syncthreads();
        // ---- phase2: AT (2 tiles/wave) + BM (2 tiles/wave) + GM1 slab (1/wave) ----
        #pragma unroll
        for (int u = 0; u < 2; ++u) {
            const int at = wid * 2 + u;   // 0..15
            const int s = (at >> 2) * 8 + (lane >> 3), t = (at & 3) * 8 + (lane & 7);
            float acc = 0.f;
            #pragma unroll
            for (int kc = 0; kc < 16; ++kc) {
                float4 a = LD4(P_KP(s, kc * 4));
                float4 bb = LD4(P_WT(t, kc * 4));
                acc += DOT4(a, bb);
            }
            P_AT(s, t) = (s < t) ? acc : 0.f;
        }
        #pragma unroll
        for (int u = 0; u < 2; ++u) {
            const int bt = wid * 2 + u;   // 0..15
            const int t = (bt >> 2) * 8 + (lane >> 3), s = (bt & 3) * 8 + (lane & 7);
            float acc = 0.f;
            #pragma unroll
            for (int kc = 0; kc < 16; ++kc) {
                float4 a = LD4(P_WT(t, kc * 4));
                float4 bb = LD4(P_NU(s, kc * 4));
                acc += DOT4(a, bb);
            }
            P_BM(t, s) = (s < t) ? acc : 0.f;
        }
        {   // GM1: wave owns GM rows [wid*4, wid*4+4) x all 64 q
            const int t = wid * 4 + (lane >> 4);
            const int q4 = (lane & 15) * 4;
            float4 acc = {0.f, 0.f, 0.f, 0.f};
            #pragma unroll
            for (int j4 = 0; j4 < 16; ++j4) {
                float4 w4 = LD4(P_WT(t, j4 * 4));
                float4 ta = LD4(P_T0(j4 * 4 + 0, q4));
                float4 tb = LD4(P_T0(j4 * 4 + 1, q4));
                float4 tc = LD4(P_T0(j4 * 4 + 2, q4));
                float4 td = LD4(P_T0(j4 * 4 + 3, q4));
                FMA4(acc, w4.x, ta); FMA4(acc, w4.y, tb);
                FMA4(acc, w4.z, tc); FMA4(acc, w4.w, td);
            }
            *(float4*)&P_GM(t, q4) = acc;
        }
        __syncthreads();
        // ---- phase3: GM += BM . RKM ----
        {
            const int t = wid * 4 + (lane >> 4);
            const int q4 = (lane & 15) * 4;
            float4 acc = {0.f, 0.f, 0.f, 0.f};
            #pragma unroll
            for (int s4 = 0; s4 < 8; ++s4) {
                float4 bm4 = LD4(P_BM(t, s4 * 4));
                float4 ra = LD4(P_RKM(s4 * 4 + 0, q4));
                float4 rb = LD4(P_RKM(s4 * 4 + 1, q4));
                float4 rc = LD4(P_RKM(s4 * 4 + 2, q4));
                float4 rd = LD4(P_RKM(s4 * 4 + 3, q4));
                FMA4(acc, bm4.x, ra); FMA4(acc, bm4.y, rb);
                FMA4(acc, bm4.z, rc); FMA4(acc, bm4.w, rd);
            }
            float4 g = LD4(P_GM(t, q4));
            g.x += acc.x; g.y += acc.y; g.z += acc.z; g.w += acc.w;
            *(float4*)&P_GM(t, q4) = g;
        }
        __syncthreads();
        // ---- phase4: wave0 forward substitution || waves1-7: P2t (emit only) ----
        if (wid == 0) {
            float g[32];
            #pragma unroll
            for (int t = 0; t < 32; ++t) g[t] = P_GM(t, lane);
            #pragma unroll
            for (int s = 0; s < 31; ++s) {
                #pragma unroll
                for (int t = s + 1; t < 32; ++t) g[t] -= P_AT(s, t) * g[s];
            }
            #pragma unroll
            for (int t = 0; t < 32; ++t) P_GM(t, lane) = g[t];
        } else if (emit) {
            for (int tile = wid - 1; tile < 16; tile += 7) {
                int t = (tile >> 2) * 8 + (lane >> 3), s = (tile & 3) * 8 + (lane & 7);
                float acc = 0.f;
                #pragma unroll
                for (int kc = 0; kc < 16; ++kc) {
                    float4 a = LD4(P_RRM(t, kc * 4));
                    float4 bb = LD4(P_RKM(s, kc * 4));
                    acc += DOT4(a, bb);
                }
                P_P2t(t, s) = (s <= t) ? acc : 0.f;
            }
        }
        __syncthreads();
        if (emit) {
            // ---- phase5: GRt[t][s] = g_s . r_t (16 tiles) ----
            for (int tile = wid; tile < 16; tile += 8) {
                int t = (tile >> 2) * 8 + (lane >> 3), s = (tile & 3) * 8 + (lane & 7);
                float acc = 0.f;
                #pragma unroll
                for (int kc = 0; kc < 16; ++kc) {
                    float4 a = LD4(P_RRM(t, kc * 4));
                    float4 bb = LD4(P_GM(s, kc * 4));
                    acc += DOT4(a, bb);
                }
                P_GRt(t, s) = (s <= t) ? acc : 0.f;
            }
            __syncthreads();
            // ---- phase6a: outputs (32 tiles; bf16 stores) ----
            for (int tile = wid; tile < 32; tile += 8) {
                int i = (tile >> 2) * 8 + (lane >> 3), t = (tile & 3) * 8 + (lane & 7);
                float a1 = 0.f, a2 = 0.f, a3 = 0.f;
                #pragma unroll
                for (int j4 = 0; j4 < 16; ++j4) {
                    float4 a = LD4(P_T0(i, j4 * 4));
                    float4 bb = LD4(P_RRM(t, j4 * 4));
                    a1 += DOT4(a, bb);
                }
                #pragma unroll
                for (int s4 = 0; s4 < 8; ++s4) {
                    float4 a = LD4(P_NUT(i, s4 * 4));
                    float4 bb = LD4(P_P2t(t, s4 * 4));
                    a2 += DOT4(a, bb);
                    float4 c = LD4(P_KPT(i, s4 * 4));
                    float4 d = LD4(P_GRt(t, s4 * 4));
                    a3 += DOT4(c, d);
                }
                float diag = 0.2f * bonus_mult[h * NN + i] * P_NUT(i, t) * P_P2t(t, t);
                outb[gbase + (size_t)(tg0 + t) * CC + i] =
                    __float2bfloat16(P_DCT(i, t) * (a1 + a2 + diag - a3));
            }
            __syncthreads();
        }
        // ---- phase6b: T0 <- dc_end * (T0 - Kap^T G + Nu^T RK) (de-transposed slabs) ----
        #pragma unroll
        for (int u = 0; u < 2; ++u) {
            const int m = wid * 2 + u;                       // 0..15
            const int pr = (m & 7) * 8 + (lane >> 3);        // 0..63
            const int q4 = (m >> 3) * 32 + (lane & 7) * 4;   // 0..60
            float4 a1 = {0.f, 0.f, 0.f, 0.f}, a2 = {0.f, 0.f, 0.f, 0.f};
            #pragma unroll
            for (int s = 0; s < 32; ++s) {
                const float kp = P_KPT(pr, s);
                const float nu = P_NUT(pr, s);
                float4 g4 = LD4(P_GM(s, q4));
                float4 rk4 = LD4(P_RKM(s, q4));
                FMA4(a1, kp, g4);
                FMA4(a2, nu, rk4);
            }
            const float dc = P_DCT(pr, 31);
            float4 t0 = LD4(P_T0(pr, q4));
            t0.x = dc * (t0.x - a1.x + a2.x);
            t0.y = dc * (t0.y - a1.y + a2.y);
            t0.z = dc * (t0.z - a1.z + a2.z);
            t0.w = dc * (t0.w - a1.w + a2.w);
            *(float4*)&P_T0(pr, q4) = t0;
        }
        __syncthreads();
    }
}

// ---------------- LayerNorm * gate (bf16 in/out) ----------------
__global__ __launch_bounds__(256) void ln_gate_kernel(const __hip_bfloat16* __restrict__ x,
                                                      const __hip_bfloat16* __restrict__ gate,
                                                      const float* __restrict__ g,
                                                      const float* __restrict__ bv,
                                                      __hip_bfloat16* __restrict__ y) {
    const int row = blockIdx.x;
    const __hip_bfloat16* xr = x + (size_t)row * CC;
    float v[4];
    float s = 0.f;
    #pragma unroll
    for (int j = 0; j < 4; ++j) { v[j] = __bfloat162float(xr[threadIdx.x + 256 * j]); s += v[j]; }
    __shared__ float red[4], red2[4];
    #pragma unroll
    for (int o = 32; o; o >>= 1) s += __shfl_xor(s, o);
    if ((threadIdx.x & 63) == 0) red[threadIdx.x >> 6] = s;
    __syncthreads();
    const float mean = (red[0] + red[1] + red[2] + red[3]) * (1.f / CC);
    float vs = 0.f;
    #pragma unroll
    for (int j = 0; j < 4; ++j) { float d = v[j] - mean; vs += d * d; }
    #pragma unroll
    for (int o = 32; o; o >>= 1) vs += __shfl_xor(vs, o);
    if ((threadIdx.x & 63) == 0) red2[threadIdx.x >> 6] = vs;
    __syncthreads();
    const float var = (red2[0] + red2[1] + red2[2] + red2[3]) * (1.f / CC);
    const float rstd = rsqrtf(var + 1e-6f);
    #pragma unroll
    for (int j = 0; j < 4; ++j) {
        const int cc = threadIdx.x + 256 * j;
        float o_ = (v[j] - mean) * rstd * g[cc] + bv[cc];
        float gt = __bfloat162float(gate[(size_t)row * CC + cc]);
        y[(size_t)row * CC + cc] = __float2bfloat16(o_ * gt);
    }
}

// ---------------- launch ----------------
extern "C" void kernel_launch(void* const* d_in, const int* in_sizes, int n_in,
                              void* d_out, int out_size, void* d_ws, size_t ws_size,
                              hipStream_t stream) {
    const float* q        = (const float*)d_in[0];
    const float* mu_r     = (const float*)d_in[4];
    const float* mu_k     = (const float*)d_in[5];
    const float* mu_v     = (const float*)d_in[6];
    const float* mu_g     = (const float*)d_in[7];
    const float* mu_a     = (const float*)d_in[8];
    const float* mu_d     = (const float*)d_in[9];
    const float* dA       = (const float*)d_in[10];
    const float* dB       = (const float*)d_in[11];
    const float* db       = (const float*)d_in[12];
    const float* aA       = (const float*)d_in[13];
    const float* aB       = (const float*)d_in[14];
    const float* ab       = (const float*)d_in[15];
    const float* gA       = (const float*)d_in[16];
    const float* gB       = (const float*)d_in[17];
    const float* rW1      = (const float*)d_in[18];
    const float* rb1      = (const float*)d_in[19];
    const float* rW2      = (const float*)d_in[20];
    const float* rb2      = (const float*)d_in[21];
    const float* kW1      = (const float*)d_in[22];
    const float* kb1      = (const float*)d_in[23];
    const float* kW2      = (const float*)d_in[24];
    const float* kb2      = (const float*)d_in[25];
    const float* vW1      = (const float*)d_in[26];
    const float* vb1      = (const float*)d_in[27];
    const float* vW2      = (const float*)d_in[28];
    const float* vb2      = (const float*)d_in[29];
    const float* oW1      = (const float*)d_in[30];
    const float* ob1      = (const float*)d_in[31];
    const float* oW2      = (const float*)d_in[32];
    const float* ob2      = (const float*)d_in[33];
    const float* rem_mult = (const float*)d_in[34];
    const float* iclr_mix = (const float*)d_in[35];
    const float* bonus_mult = (const float*)d_in[36];
    const float* ln_g     = (const float*)d_in[37];
    const float* ln_b     = (const float*)d_in[38];
    float* out = (float*)d_out;

    // ---- workspace arena (~220 MB) ----
    char* p = (char*)d_ws;
    auto alloc = [&](size_t bytes) { char* r = p; p += (bytes + 255) & ~(size_t)255; return r; };
    float* fb_all  = (float*)alloc((size_t)3 * EPAD * 4);
    float* c2_all  = (float*)alloc((size_t)3 * CC * 4);
    float* lt_all  = (float*)alloc((size_t)3 * LL * 4);
    float* cb2_all = (float*)alloc((size_t)3 * CC * 4);
    __hip_bfloat16* qb      = (__hip_bfloat16*)alloc((size_t)MM * CC * 2);
    __hip_bfloat16* W1T_all = (__hip_bfloat16*)alloc((size_t)3 * EPAD * CC * 2);
    __hip_bfloat16* W2T_all = (__hip_bfloat16*)alloc((size_t)3 * CC * EPAD * 2);
    __hip_bfloat16* Hb      = (__hip_bfloat16*)alloc((size_t)MM * 3 * EPAD * 2);
    __hip_bfloat16* rkvb    = (__hip_bfloat16*)alloc((size_t)3 * MM * CC * 2);   // r,k,v bf16
    __hip_bfloat16* gadbuf  = (__hip_bfloat16*)alloc((size_t)3 * MM * CC * 2);
    __hip_bfloat16* gbuf = gadbuf;
    __hip_bfloat16* abuf = gadbuf + (size_t)MM * CC;
    __hip_bfloat16* dbuf = gadbuf + (size_t)2 * MM * CC;
    __hip_bfloat16* rbuf = rkvb;
    __hip_bfloat16* kbuf = rkvb + (size_t)MM * CC;
    __hip_bfloat16* vbuf = rkvb + (size_t)2 * MM * CC;
    // time-multiplexed tenants of the rkvb arena (48 MB):
    float*          pp      = (float*)rkvb;                                 // fold partials (dies before AT/BT)
    __hip_bfloat16* AT_all  = (__hip_bfloat16*)((char*)rkvb + (1 << 18));   // LoRA A^T
    __hip_bfloat16* BT_all  = (__hip_bfloat16*)((char*)rkvb + (1 << 18) + 786432);
    __hip_bfloat16* oW1T    = (__hip_bfloat16*)rkvb;                        // written after recurrence
    __hip_bfloat16* oW2T    = (__hip_bfloat16*)((char*)rkvb + 4194304);
    __hip_bfloat16* tgad    = Hb;
    __hip_bfloat16* robuf   = (__hip_bfloat16*)out;                          // recurrence out (bf16 in d_out scratch)

    const dim3 blk(256);
    const dim3 tblk(32, 8);

    gather3<<<dim3(4), blk, 0, stream>>>(rb2, kb2, vb2, cb2_all);

    fold_pass1_z<<<dim3(20, 16, 3), blk, 0, stream>>>(mu_r, mu_k, mu_v, rW1, kW1, vW1,
                                                      pp, EE, EE, EPAD, 16 * EPAD);
    fold_pass2_z<<<dim3(5, 1, 3), blk, 0, stream>>>(pp, rb1, kb1, vb1, fb_all,
                                                    16, EPAD, 16 * EPAD, EE, EPAD, EPAD);
    fold_pass1_z<<<dim3(2, 16, 3), blk, 0, stream>>>(mu_g, mu_a, mu_d, gA, aA, dA,
                                                     pp, LL, LL, EPAD, 16 * EPAD);
    fold_pass2_z<<<dim3(1, 1, 3), dim3(128), 0, stream>>>(pp, nullptr, nullptr, nullptr, lt_all,
                                                          16, EPAD, 16 * EPAD, LL, LL, LL);
    fold_pass1_z<<<dim3(16, 2, 3), blk, 0, stream>>>(lt_all, lt_all + LL, lt_all + 2 * LL, gB, aB, dB,
                                                     pp, CC, CC, EPAD, 16 * EPAD);
    fold_pass2_z<<<dim3(4, 1, 3), blk, 0, stream>>>(pp, nullptr, ab, db, c2_all,
                                                    2, EPAD, 16 * EPAD, CC, CC, CC);

    transpose_cast_z<<<dim3(32, 40, 3), tblk, 0, stream>>>(rW1, kW1, vW1, W1T_all,
                                                           (size_t)EPAD * CC, CC, EE, CC, EPAD);
    transpose_cast_z<<<dim3(40, 32, 3), tblk, 0, stream>>>(rW2, kW2, vW2, W2T_all,
                                                           (size_t)CC * EPAD, EE, CC, EPAD, CC);
    transpose_cast_z<<<dim3(32, 4, 3), tblk, 0, stream>>>(gA, aA, dA, AT_all,
                                                          (size_t)LL * CC, CC, LL, CC, LL);
    transpose_cast_z<<<dim3(4, 32, 3), tblk, 0, stream>>>(gB, aB, dB, BT_all,
                                                          (size_t)CC * LL, LL, CC, LL, CC);

    cast_f32_bf16<<<dim3(MM * CC / 4 / 256), blk, 0, stream>>>(q, qb, MM * CC / 4);

    gemm_mfma<0,-1,1,0><<<dim3(3, 64, 1), blk, 0, stream>>>(qb, AT_all, nullptr, tgad,
                                                            MM, 384, CC, CC, CC, 384, 0, 0, 0, 0);
    gemm_mfma<2,3,1,0><<<dim3(8, 64, 3), blk, 0, stream>>>(tgad, BT_all, c2_all, gadbuf,
                                                           MM, CC, LL, 384, LL, CC,
                                                           LL, (size_t)CC * LL, CC, (size_t)MM * CC);

    gemm_mfma<1,-1,1,0><<<dim3(30, 64, 1), blk, 0, stream>>>(qb, W1T_all, fb_all, Hb,
                                                             MM, 3 * EPAD, CC, CC, CC, 3 * EPAD, 0, 0, 0, 0);
    gemm_mfma<0,-1,1,0><<<dim3(8, 64, 3), blk, 0, stream>>>(Hb, W2T_all, cb2_all, rkvb,
                                                            MM, CC, EPAD, 3 * EPAD, EPAD, CC,
                                                            EPAD, (size_t)CC * EPAD, CC, (size_t)MM * CC);

    recurrence_chunked<<<dim3(BB * HH * NSEG), dim3(512), 0, stream>>>(
        kbuf, abuf, dbuf, vbuf, rbuf, rem_mult, iclr_mix, bonus_mult, robuf);

    transpose_cast_z<<<dim3(32, 40, 1), tblk, 0, stream>>>(oW1, oW1, oW1, oW1T,
                                                           0, CC, EE, CC, EPAD);
    transpose_cast_z<<<dim3(40, 32, 1), tblk, 0, stream>>>(oW2, oW2, oW2, oW2T,
                                                           0, EE, CC, EPAD, CC);

    ln_gate_kernel<<<dim3(MM), blk, 0, stream>>>(robuf, gbuf, ln_g, ln_b, qb);

    gemm_mfma<1,-1,1,1><<<dim3(10, 64, 1), blk, 0, stream>>>(qb, oW1T, ob1, Hb,
                                                             MM, EE, CC, CC, CC, EPAD, 0, 0, 0, 0);
    gemm_mfma<0,-1,0,0><<<dim3(8, 64, 1), blk, 0, stream>>>(Hb, oW2T, ob2, out,
                                                            MM, CC, EPAD, EPAD, EPAD, CC, 0, 0, 0, 0);
}